// Round 2
// baseline (522.040 us; speedup 1.0000x reference)
//
#include <hip/hip_runtime.h>
#include <math.h>

#define NPOS 110592   // 48*48*48
#define EPS 1e-5f

// workspace layout (float element offsets)
constexpr long O_WT    = 0;          // 112*128 = 14336  (WT[c][oc], oc: 0..63 q, 64..79 k, 80..111 v)
constexpr long O_WPT   = 14336;      // 27*16 = 432      (wposT[o][k])
constexpr long O_SARR  = 14768;      // 96  (scale: 0..63 q, 64..95 v)
constexpr long O_TARR  = 14864;      // 96  (shift)
constexpr long O_STPS  = 14960;      // 96*8 sum partials
constexpr long O_STPQ  = 15728;      // 96*8 sumsq partials
constexpr long O_RMP   = 16496;      // 32*8 rowmax partials
constexpr long O_RMAX  = 16752;      // 32
constexpr long O_RZP   = 16784;      // 32*8 rowsum partials
constexpr long O_RZI   = 17040;      // 32 (1/Z)
constexpr long O_LAMC  = 17072;      // 2*16*32 = 1024
constexpr long O_LAMCP = 18096;      // 2*432*512 = 442368
constexpr long O_Q     = 460464;     // 2*64*NPOS = 14155776
constexpr long O_K     = 14616240;   // 2*16*NPOS = 3538944
constexpr long O_V     = 18155184;   // 2*32*NPOS = 7077888
// total 25233072 floats = 100.9 MB

// ---------------- setup: transpose weights ----------------
__global__ __launch_bounds__(256) void ksetup(const float* Wq, const float* Wk, const float* Wv,
                                              const float* Wpos, float* ws) {
    int i = blockIdx.x * 256 + threadIdx.x;
    if (i < 14336) {
        int c = i / 112, oc = i - c * 112;
        float v;
        if (oc < 64)       v = Wq[oc * 128 + c];
        else if (oc < 80)  v = Wk[(oc - 64) * 128 + c];
        else               v = Wv[(oc - 80) * 128 + c];
        ws[O_WT + i] = v;
    } else if (i < 14336 + 432) {
        int j = i - 14336;
        int o = j >> 4, k = j & 15;
        ws[O_WPT + j] = Wpos[k * 27 + o];   // Wpos[k][0][od][oh][ow], o = od*9+oh*3+ow
    }
}

// ---------------- projection: q_raw/k_raw/v_raw = W * x ----------------
__global__ __launch_bounds__(256) void kproj(const float* __restrict__ x, const float* __restrict__ ws,
                                             float* __restrict__ qr, float* __restrict__ kr,
                                             float* __restrict__ vr) {
    __shared__ float xs[128 * 64];
    const float* WT = ws + O_WT;
    int blk = blockIdx.x;                 // 0..3455
    int b = blk / 1728, tile = blk - b * 1728;
    long base = (long)b * 128 * NPOS + (long)tile * 64;
    int tid = threadIdx.x;
    for (int i = tid; i < 128 * 64; i += 256) {
        int c = i >> 6, p = i & 63;
        xs[c * 64 + p] = x[base + (long)c * NPOS + p];
    }
    __syncthreads();
    int lane = tid & 63;
    int w = __builtin_amdgcn_readfirstlane(tid >> 6);   // wave id, provably uniform
    float acc[28];
#pragma unroll
    for (int i = 0; i < 28; ++i) acc[i] = 0.f;
    const float* wrow = WT + w * 28;
#pragma unroll 4
    for (int c = 0; c < 128; ++c) {
        float xv = xs[c * 64 + lane];
#pragma unroll
        for (int i = 0; i < 28; ++i) acc[i] = fmaf(wrow[c * 112 + i], xv, acc[i]);
    }
    int pos = tile * 64 + lane;
#pragma unroll
    for (int i = 0; i < 28; ++i) {
        int oc = w * 28 + i;
        float val = acc[i];
        if (oc < 64)      qr[((long)b * 64 + oc) * NPOS + pos] = val;
        else if (oc < 80) kr[((long)b * 16 + (oc - 64)) * NPOS + pos] = val;
        else              vr[((long)b * 32 + (oc - 80)) * NPOS + pos] = val;
    }
}

// ---------------- BN stat partials (96 channels x 8 slabs) ----------------
__global__ __launch_bounds__(256) void kstats(const float* __restrict__ qr, const float* __restrict__ vr,
                                              float* __restrict__ ws) {
    __shared__ float red[256], red2[256];
    int ch = blockIdx.x >> 3, slab = blockIdx.x & 7;
    int b = slab >> 2;
    int p0 = (slab & 3) * 27648;
    const float* src = (ch < 64) ? qr + ((long)b * 64 + ch) * NPOS
                                 : vr + ((long)b * 32 + (ch - 64)) * NPOS;
    float s = 0.f, q = 0.f;
    for (int i = threadIdx.x; i < 27648; i += 256) {
        float v = src[p0 + i];
        s += v; q = fmaf(v, v, q);
    }
    red[threadIdx.x] = s; red2[threadIdx.x] = q;
    __syncthreads();
    for (int st = 128; st > 0; st >>= 1) {
        if (threadIdx.x < st) { red[threadIdx.x] += red[threadIdx.x + st]; red2[threadIdx.x] += red2[threadIdx.x + st]; }
        __syncthreads();
    }
    if (threadIdx.x == 0) {
        ws[O_STPS + ch * 8 + slab] = red[0];
        ws[O_STPQ + ch * 8 + slab] = red2[0];
    }
}

// ---------------- softmax rowmax partials (32 rows x 8 slabs) ----------------
__global__ __launch_bounds__(256) void krmaxp(const float* __restrict__ kr, float* __restrict__ ws) {
    __shared__ float red[256];
    int row = blockIdx.x >> 3, slab = blockIdx.x & 7;
    int b = row >> 4, kk = row & 15;
    const float* src = kr + ((long)b * 16 + kk) * NPOS + slab * 13824;
    float m = -1e30f;
    for (int i = threadIdx.x; i < 13824; i += 256) m = fmaxf(m, src[i]);
    red[threadIdx.x] = m;
    __syncthreads();
    for (int st = 128; st > 0; st >>= 1) {
        if (threadIdx.x < st) red[threadIdx.x] = fmaxf(red[threadIdx.x], red[threadIdx.x + st]);
        __syncthreads();
    }
    if (threadIdx.x == 0) ws[O_RMP + row * 8 + slab] = red[0];
}

// ---------------- finalize BN stats + rowmax ----------------
__global__ __launch_bounds__(128) void kfin1(const float* gq, const float* bq, const float* gv,
                                             const float* bv, float* ws) {
    int tid = threadIdx.x;
    if (tid < 96) {
        float s = 0.f, q = 0.f;
        for (int j = 0; j < 8; ++j) { s += ws[O_STPS + tid * 8 + j]; q += ws[O_STPQ + tid * 8 + j]; }
        const float inv_n = 1.f / 221184.f;
        float mean = s * inv_n;
        float var = q * inv_n - mean * mean;
        float g, bb;
        if (tid < 64) { g = gq[tid]; bb = bq[tid]; }
        else          { g = gv[tid - 64]; bb = bv[tid - 64]; }
        float sc = g * rsqrtf(var + EPS);
        ws[O_SARR + tid] = sc;
        ws[O_TARR + tid] = bb - mean * sc;
    } else if (tid < 128) {
        int row = tid - 96;
        float m = -1e30f;
        for (int j = 0; j < 8; ++j) m = fmaxf(m, ws[O_RMP + row * 8 + j]);
        ws[O_RMAX + row] = m;
    }
}

// ---------------- softmax denom partials ----------------
__global__ __launch_bounds__(256) void krzp(const float* __restrict__ kr, float* __restrict__ ws) {
    __shared__ float red[256];
    int row = blockIdx.x >> 3, slab = blockIdx.x & 7;
    int b = row >> 4, kk = row & 15;
    float rmax = ws[O_RMAX + row];
    const float* src = kr + ((long)b * 16 + kk) * NPOS + slab * 13824;
    float s = 0.f;
    for (int i = threadIdx.x; i < 13824; i += 256) s += expf(src[i] - rmax);
    red[threadIdx.x] = s;
    __syncthreads();
    for (int st = 128; st > 0; st >>= 1) {
        if (threadIdx.x < st) red[threadIdx.x] += red[threadIdx.x + st];
        __syncthreads();
    }
    if (threadIdx.x == 0) ws[O_RZP + row * 8 + slab] = red[0];
}

__global__ __launch_bounds__(64) void kfin2(float* ws) {
    int tid = threadIdx.x;
    if (tid < 32) {
        float s = 0.f;
        for (int j = 0; j < 8; ++j) s += ws[O_RZP + tid * 8 + j];
        ws[O_RZI + tid] = 1.f / s;
    }
}

// ---------------- lam_c partials: S[k][v] = sum_p e[k][p] * v_raw[v][p] ----------------
__global__ __launch_bounds__(256) void klamcp(const float* __restrict__ kr, const float* __restrict__ vr,
                                              const float* __restrict__ ws, float* __restrict__ lamcp) {
    __shared__ float es[16 * 256];
    const float* rmax = ws + O_RMAX;
    int bid = blockIdx.x;                  // 0..863
    int b = bid / 432, chunk = bid - b * 432;
    long p0 = (long)chunk * 256;
    int tid = threadIdx.x;
    for (int i = tid; i < 16 * 256; i += 256) {
        int r = i >> 8, p = i & 255;
        es[i] = expf(kr[((long)b * 16 + r) * NPOS + p0 + p] - rmax[b * 16 + r]);
    }
    __syncthreads();
    int vp = tid >> 4, pl = tid & 15;      // v-pair 0..15, position lane 0..15
    const float* v0p = vr + ((long)b * 32 + 2 * vp) * NPOS + p0;
    const float* v1p = v0p + NPOS;
    float acc0[16], acc1[16];
#pragma unroll
    for (int k = 0; k < 16; ++k) { acc0[k] = 0.f; acc1[k] = 0.f; }
    for (int j = 0; j < 16; ++j) {
        int p = pl + 16 * j;
        float v0 = v0p[p], v1 = v1p[p];
#pragma unroll
        for (int k = 0; k < 16; ++k) {
            float e = es[k * 256 + p];
            acc0[k] = fmaf(e, v0, acc0[k]);
            acc1[k] = fmaf(e, v1, acc1[k]);
        }
    }
    // reduce partial sums across the 16 position-lanes (pl) of each v-pair group.
    // lanes with the same vp are contiguous 16-lane groups inside the wave, so
    // xor-butterfly with masks 1,2,4,8 stays inside the group.
#pragma unroll
    for (int m = 1; m < 16; m <<= 1) {
#pragma unroll
        for (int k = 0; k < 16; ++k) {
            acc0[k] += __shfl_xor(acc0[k], m, 64);
            acc1[k] += __shfl_xor(acc1[k], m, 64);
        }
    }
    if (pl == 0) {
        long base = (long)bid * 512;
#pragma unroll
        for (int k = 0; k < 16; ++k) {
            lamcp[base + k * 32 + 2 * vp]     = acc0[k];
            lamcp[base + k * 32 + 2 * vp + 1] = acc1[k];
        }
    }
}

// ---------------- reduce lam_c partials + fold BN + 1/Z ----------------
__global__ __launch_bounds__(256) void klamcred(float* ws) {
    int out = blockIdx.x * 256 + threadIdx.x;   // 0..1023
    if (out >= 1024) return;
    int b = out >> 9, idx = out & 511;
    int kk = idx >> 5, v = idx & 31;
    const float* lamcp = ws + O_LAMCP;
    float S = 0.f;
    for (int c = 0; c < 432; ++c) S += lamcp[((long)b * 432 + c) * 512 + idx];
    float sv = ws[O_SARR + 64 + v], tv = ws[O_TARR + 64 + v];
    ws[O_LAMC + out] = sv * S * ws[O_RZI + b * 16 + kk] + tv;
}

// ---------------- final fused: conv (lam_p) + q*(lam_c + lam_p) ----------------
// tile (d,h,w) = (1,4,16) -> 64 positions; halo (3,6,18) = 324 per v-channel
__global__ __launch_bounds__(256, 2) void kfinal(const float* __restrict__ qr, const float* __restrict__ vr,
                                                 const float* __restrict__ ws, float* __restrict__ y) {
    __shared__ float vbn[32 * 324];
    __shared__ float qs[64 * 64];
    const float* sarr = ws + O_SARR;
    const float* tarr = ws + O_TARR;
    const float* lamc = ws + O_LAMC;
    const float* wpt  = ws + O_WPT;

    int bid = blockIdx.x;                  // 0..3455
    int b = bid / 1728, t = bid - b * 1728;   // tiles: d 48 x h 12 x w 3
    int td = t / 36, r = t - td * 36;
    int th = r / 3, tw = r - th * 3;
    int d0 = td, h0 = th * 4, w0 = tw * 16;
    int tid = threadIdx.x;

    // halo load of BN'd v (zero pad outside volume, AFTER BN)
    for (int i = tid; i < 32 * 324; i += 256) {
        int v = i / 324, z = i - v * 324;
        int zd = z / 108, rr = z - zd * 108;
        int zh = rr / 18, zw = rr - zh * 18;
        int gd = d0 - 1 + zd, gh = h0 - 1 + zh, gw = w0 - 1 + zw;
        float val = 0.f;
        if ((unsigned)gd < 48u && (unsigned)gh < 48u && (unsigned)gw < 48u) {
            float raw = vr[((long)b * 32 + v) * NPOS + gd * 2304 + gh * 48 + gw];
            val = fmaf(raw, sarr[64 + v], tarr[64 + v]);
        }
        vbn[i] = val;
    }
    // stage BN'd q tile: 64 ch x 64 pos
    for (int i = tid; i < 64 * 64; i += 256) {
        int ch = i >> 6, p = i & 63;
        int lh = p >> 4, lw = p & 15;
        float raw = qr[((long)b * 64 + ch) * NPOS + d0 * 2304 + (h0 + lh) * 48 + (w0 + lw)];
        qs[i] = fmaf(raw, sarr[ch], tarr[ch]);
    }
    __syncthreads();

    int lane = tid & 63;
    int wv = __builtin_amdgcn_readfirstlane(tid >> 6);
    int v8 = wv * 8;
    int lh = lane >> 4, lw = lane & 15;

    float qreg[64];
#pragma unroll
    for (int ch = 0; ch < 64; ++ch) qreg[ch] = qs[ch * 64 + lane];

    float acc[32];
#pragma unroll
    for (int i = 0; i < 32; ++i) acc[i] = 0.f;

    // y_c: acc[h][vi] = sum_k q[h][k] * lam_c[k][v8+vi]   (lam_c via scalar loads)
    const float* lc = lamc + b * 512;
    for (int k = 0; k < 16; ++k) {
#pragma unroll
        for (int h = 0; h < 4; ++h) {
            float qv = qreg[h * 16 + k];
#pragma unroll
            for (int vi = 0; vi < 8; ++vi)
                acc[h * 8 + vi] = fmaf(qv, lc[k * 32 + v8 + vi], acc[h * 8 + vi]);
        }
    }

    // lam_p conv + contraction, one v at a time
    for (int vi = 0; vi < 8; ++vi) {
        int v = v8 + vi;
        const float* vb = vbn + v * 324;
        float strip[27];
#pragma unroll
        for (int od = 0; od < 3; ++od)
#pragma unroll
            for (int oh = 0; oh < 3; ++oh)
#pragma unroll
                for (int ow = 0; ow < 3; ++ow)
                    strip[od * 9 + oh * 3 + ow] = vb[od * 108 + (lh + oh) * 18 + (lw + ow)];
        float lamp[16];
#pragma unroll
        for (int k = 0; k < 16; ++k) lamp[k] = 0.f;
#pragma unroll
        for (int o = 0; o < 27; ++o) {
            float sv = strip[o];
#pragma unroll
            for (int k = 0; k < 16; ++k) lamp[k] = fmaf(wpt[o * 16 + k], sv, lamp[k]);
        }
#pragma unroll
        for (int h = 0; h < 4; ++h) {
            float a = 0.f;
#pragma unroll
            for (int k = 0; k < 16; ++k) a = fmaf(qreg[h * 16 + k], lamp[k], a);
            acc[h * 8 + vi] += a;
        }
    }

    long pbase = (long)b * 128 * NPOS + d0 * 2304 + (h0 + lh) * 48 + (w0 + lw);
#pragma unroll
    for (int h = 0; h < 4; ++h)
#pragma unroll
        for (int vi = 0; vi < 8; ++vi)
            y[pbase + (long)(h * 32 + v8 + vi) * NPOS] = acc[h * 8 + vi];
}

extern "C" void kernel_launch(void* const* d_in, const int* in_sizes, int n_in,
                              void* d_out, int out_size, void* d_ws, size_t ws_size,
                              hipStream_t stream) {
    const float* x    = (const float*)d_in[0];
    const float* Wq   = (const float*)d_in[1];
    const float* Wk   = (const float*)d_in[2];
    const float* Wv   = (const float*)d_in[3];
    const float* Wpos = (const float*)d_in[4];
    const float* gq   = (const float*)d_in[5];
    const float* bq   = (const float*)d_in[6];
    const float* gv   = (const float*)d_in[7];
    const float* bv   = (const float*)d_in[8];
    float* ws = (float*)d_ws;
    float* y  = (float*)d_out;
    float* qr = ws + O_Q;
    float* kr = ws + O_K;
    float* vr = ws + O_V;

    ksetup  <<<58,   256, 0, stream>>>(Wq, Wk, Wv, Wpos, ws);
    kproj   <<<3456, 256, 0, stream>>>(x, ws, qr, kr, vr);
    kstats  <<<768,  256, 0, stream>>>(qr, vr, ws);
    krmaxp  <<<256,  256, 0, stream>>>(kr, ws);
    kfin1   <<<1,    128, 0, stream>>>(gq, bq, gv, bv, ws);
    krzp    <<<256,  256, 0, stream>>>(kr, ws);
    kfin2   <<<1,    64,  0, stream>>>(ws);
    klamcp  <<<864,  256, 0, stream>>>(kr, vr, ws, ws + O_LAMCP);
    klamcred<<<4,    256, 0, stream>>>(ws);
    kfinal  <<<3456, 256, 0, stream>>>(qr, vr, ws, y);
}

// Round 3
// 372.396 us; speedup vs baseline: 1.4018x; 1.4018x over previous
//
#include <hip/hip_runtime.h>
#include <math.h>

#define NPOS 110592   // 48*48*48
#define EPS 1e-5f

// workspace layout (float element offsets)
constexpr long O_WT    = 0;          // 112*128 = 14336  (WT[c][oc], oc: 0..63 q, 64..79 k, 80..111 v)
constexpr long O_WPT   = 14336;      // 27*16 = 432      (wposT[o][k])
constexpr long O_SARR  = 14768;      // 96  (scale: 0..63 q, 64..95 v)
constexpr long O_TARR  = 14864;      // 96  (shift)
constexpr long O_STPS  = 14960;      // 96*8 sum partials
constexpr long O_STPQ  = 15728;      // 96*8 sumsq partials
constexpr long O_RMP   = 16496;      // 32*8 rowmax partials
constexpr long O_RMAX  = 16752;      // 32
constexpr long O_RZP   = 16784;      // 32*8 rowsum partials
constexpr long O_RZI   = 17040;      // 32 (1/Z)
constexpr long O_LAMC  = 17072;      // 2*16*32 = 1024
constexpr long O_LAMCP = 18096;      // 2*216*512 = 221184
constexpr long O_SW    = 239280;     // 4*27*16 = 1728   (s_q-folded conv weights)
constexpr long O_CW    = 241008;     // 108 (+pad)       (t_q-folded conv bias)
constexpr long O_LAMC2 = 241120;     // 2*4*16*32 = 4096 (s_q-folded lam_c)
constexpr long O_BC    = 245216;     // 2*4*32 = 256     (t_q-folded lam_c bias)
constexpr long O_Q     = 460464;     // 2*64*NPOS = 14155776
constexpr long O_K     = 14616240;   // 2*16*NPOS = 3538944
constexpr long O_V     = 18155184;   // 2*32*NPOS = 7077888
// total 25233072 floats = 100.9 MB (unchanged)

// ---------------- setup: transpose weights ----------------
__global__ __launch_bounds__(256) void ksetup(const float* Wq, const float* Wk, const float* Wv,
                                              const float* Wpos, float* ws) {
    int i = blockIdx.x * 256 + threadIdx.x;
    if (i < 14336) {
        int c = i / 112, oc = i - c * 112;
        float v;
        if (oc < 64)       v = Wq[oc * 128 + c];
        else if (oc < 80)  v = Wk[(oc - 64) * 128 + c];
        else               v = Wv[(oc - 80) * 128 + c];
        ws[O_WT + i] = v;
    } else if (i < 14336 + 432) {
        int j = i - 14336;
        int o = j >> 4, k = j & 15;
        ws[O_WPT + j] = Wpos[k * 27 + o];   // Wpos[k][0][od][oh][ow], o = od*9+oh*3+ow
    }
}

// ---------------- projection: q_raw/k_raw/v_raw = W * x ----------------
__global__ __launch_bounds__(256) void kproj(const float* __restrict__ x, const float* __restrict__ ws,
                                             float* __restrict__ qr, float* __restrict__ kr,
                                             float* __restrict__ vr) {
    __shared__ float xs[128 * 64];
    const float* WT = ws + O_WT;
    int blk = blockIdx.x;                 // 0..3455
    int b = blk / 1728, tile = blk - b * 1728;
    long base = (long)b * 128 * NPOS + (long)tile * 64;
    int tid = threadIdx.x;
    for (int i = tid; i < 128 * 64; i += 256) {
        int c = i >> 6, p = i & 63;
        xs[c * 64 + p] = x[base + (long)c * NPOS + p];
    }
    __syncthreads();
    int lane = tid & 63;
    int w = __builtin_amdgcn_readfirstlane(tid >> 6);   // wave id, provably uniform
    float acc[28];
#pragma unroll
    for (int i = 0; i < 28; ++i) acc[i] = 0.f;
    const float* wrow = WT + w * 28;
#pragma unroll 4
    for (int c = 0; c < 128; ++c) {
        float xv = xs[c * 64 + lane];
#pragma unroll
        for (int i = 0; i < 28; ++i) acc[i] = fmaf(wrow[c * 112 + i], xv, acc[i]);
    }
    int pos = tile * 64 + lane;
#pragma unroll
    for (int i = 0; i < 28; ++i) {
        int oc = w * 28 + i;
        float val = acc[i];
        if (oc < 64)      qr[((long)b * 64 + oc) * NPOS + pos] = val;
        else if (oc < 80) kr[((long)b * 16 + (oc - 64)) * NPOS + pos] = val;
        else              vr[((long)b * 32 + (oc - 80)) * NPOS + pos] = val;
    }
}

// ---------------- BN stat partials (96 channels x 8 slabs) ----------------
__global__ __launch_bounds__(256) void kstats(const float* __restrict__ qr, const float* __restrict__ vr,
                                              float* __restrict__ ws) {
    __shared__ float red[256], red2[256];
    int ch = blockIdx.x >> 3, slab = blockIdx.x & 7;
    int b = slab >> 2;
    int p0 = (slab & 3) * 27648;
    const float* src = (ch < 64) ? qr + ((long)b * 64 + ch) * NPOS
                                 : vr + ((long)b * 32 + (ch - 64)) * NPOS;
    const float4* src4 = (const float4*)(src + p0);
    float s = 0.f, q = 0.f;
    for (int i = threadIdx.x; i < 6912; i += 256) {
        float4 v = src4[i];
        s += v.x + v.y + v.z + v.w;
        q = fmaf(v.x, v.x, q); q = fmaf(v.y, v.y, q);
        q = fmaf(v.z, v.z, q); q = fmaf(v.w, v.w, q);
    }
    red[threadIdx.x] = s; red2[threadIdx.x] = q;
    __syncthreads();
    for (int st = 128; st > 0; st >>= 1) {
        if (threadIdx.x < st) { red[threadIdx.x] += red[threadIdx.x + st]; red2[threadIdx.x] += red2[threadIdx.x + st]; }
        __syncthreads();
    }
    if (threadIdx.x == 0) {
        ws[O_STPS + ch * 8 + slab] = red[0];
        ws[O_STPQ + ch * 8 + slab] = red2[0];
    }
}

// ---------------- softmax rowmax partials (32 rows x 8 slabs) ----------------
__global__ __launch_bounds__(256) void krmaxp(const float* __restrict__ kr, float* __restrict__ ws) {
    __shared__ float red[256];
    int row = blockIdx.x >> 3, slab = blockIdx.x & 7;
    int b = row >> 4, kk = row & 15;
    const float4* src = (const float4*)(kr + ((long)b * 16 + kk) * NPOS + slab * 13824);
    float m = -1e30f;
    for (int i = threadIdx.x; i < 3456; i += 256) {
        float4 v = src[i];
        m = fmaxf(m, fmaxf(fmaxf(v.x, v.y), fmaxf(v.z, v.w)));
    }
    red[threadIdx.x] = m;
    __syncthreads();
    for (int st = 128; st > 0; st >>= 1) {
        if (threadIdx.x < st) red[threadIdx.x] = fmaxf(red[threadIdx.x], red[threadIdx.x + st]);
        __syncthreads();
    }
    if (threadIdx.x == 0) ws[O_RMP + row * 8 + slab] = red[0];
}

// ---------------- finalize BN stats + rowmax ----------------
__global__ __launch_bounds__(128) void kfin1(const float* gq, const float* bq, const float* gv,
                                             const float* bv, float* ws) {
    int tid = threadIdx.x;
    if (tid < 96) {
        float s = 0.f, q = 0.f;
        for (int j = 0; j < 8; ++j) { s += ws[O_STPS + tid * 8 + j]; q += ws[O_STPQ + tid * 8 + j]; }
        const float inv_n = 1.f / 221184.f;
        float mean = s * inv_n;
        float var = q * inv_n - mean * mean;
        float g, bb;
        if (tid < 64) { g = gq[tid]; bb = bq[tid]; }
        else          { g = gv[tid - 64]; bb = bv[tid - 64]; }
        float sc = g * rsqrtf(var + EPS);
        ws[O_SARR + tid] = sc;
        ws[O_TARR + tid] = bb - mean * sc;
    } else if (tid < 128) {
        int row = tid - 96;
        float m = -1e30f;
        for (int j = 0; j < 8; ++j) m = fmaxf(m, ws[O_RMP + row * 8 + j]);
        ws[O_RMAX + row] = m;
    }
}

// ---------------- softmax denom partials ----------------
__global__ __launch_bounds__(256) void krzp(const float* __restrict__ kr, float* __restrict__ ws) {
    __shared__ float red[256];
    int row = blockIdx.x >> 3, slab = blockIdx.x & 7;
    int b = row >> 4, kk = row & 15;
    float rmax = ws[O_RMAX + row];
    const float4* src = (const float4*)(kr + ((long)b * 16 + kk) * NPOS + slab * 13824);
    float s = 0.f;
    for (int i = threadIdx.x; i < 3456; i += 256) {
        float4 v = src[i];
        s += expf(v.x - rmax) + expf(v.y - rmax) + expf(v.z - rmax) + expf(v.w - rmax);
    }
    red[threadIdx.x] = s;
    __syncthreads();
    for (int st = 128; st > 0; st >>= 1) {
        if (threadIdx.x < st) red[threadIdx.x] += red[threadIdx.x + st];
        __syncthreads();
    }
    if (threadIdx.x == 0) ws[O_RZP + row * 8 + slab] = red[0];
}

// ---------------- finalize Z, fold BN into conv weights ----------------
__global__ __launch_bounds__(256) void kfin2(float* ws) {
    int tid = threadIdx.x;
    if (tid < 32) {
        float s = 0.f;
        for (int j = 0; j < 8; ++j) s += ws[O_RZP + tid * 8 + j];
        ws[O_RZI + tid] = 1.f / s;
    }
    // sw[h][o][k] = s_q[h*16+k] * w[o][k]
    for (int i = tid; i < 1728; i += 256) {
        int h = i / 432, r = i - h * 432, o = r >> 4, k = r & 15;
        ws[O_SW + i] = ws[O_SARR + h * 16 + k] * ws[O_WPT + o * 16 + k];
    }
    // cw[h][o] = sum_k t_q[h*16+k] * w[o][k]
    if (tid < 108) {
        int h = tid / 27, o = tid - h * 27;
        float s = 0.f;
        for (int k = 0; k < 16; ++k) s += ws[O_TARR + h * 16 + k] * ws[O_WPT + o * 16 + k];
        ws[O_CW + tid] = s;
    }
}

// ---------------- lam_c partials: S[k][v] = sum_p e[k][p] * v_raw[v][p] ----------------
__global__ __launch_bounds__(256) void klamcp(const float* __restrict__ kr, const float* __restrict__ vr,
                                              const float* __restrict__ ws, float* __restrict__ lamcp) {
    __shared__ float es[16 * 512];
    const float* rmax = ws + O_RMAX;
    int bid = blockIdx.x;                  // 0..431
    int b = bid / 216, chunk = bid - b * 216;
    long p0 = (long)chunk * 512;
    int tid = threadIdx.x;
    for (int i = tid; i < 16 * 512; i += 256) {
        int r = i >> 9, p = i & 511;
        es[i] = expf(kr[((long)b * 16 + r) * NPOS + p0 + p] - rmax[b * 16 + r]);
    }
    __syncthreads();
    int vp = tid >> 4, pl = tid & 15;      // v-pair 0..15, position lane 0..15
    const float* v0p = vr + ((long)b * 32 + 2 * vp) * NPOS + p0;
    const float* v1p = v0p + NPOS;
    float acc0[16], acc1[16];
#pragma unroll
    for (int k = 0; k < 16; ++k) { acc0[k] = 0.f; acc1[k] = 0.f; }
    for (int j = 0; j < 32; ++j) {
        int p = pl + 16 * j;
        float v0 = v0p[p], v1 = v1p[p];
#pragma unroll
        for (int k = 0; k < 16; ++k) {
            float e = es[k * 512 + p];
            acc0[k] = fmaf(e, v0, acc0[k]);
            acc1[k] = fmaf(e, v1, acc1[k]);
        }
    }
    // reduce across the 16 position-lanes of each v-pair group
#pragma unroll
    for (int m = 1; m < 16; m <<= 1) {
#pragma unroll
        for (int k = 0; k < 16; ++k) {
            acc0[k] += __shfl_xor(acc0[k], m, 64);
            acc1[k] += __shfl_xor(acc1[k], m, 64);
        }
    }
    if (pl == 0) {
        long base = (long)bid * 512;
#pragma unroll
        for (int k = 0; k < 16; ++k) {
            lamcp[base + k * 32 + 2 * vp]     = acc0[k];
            lamcp[base + k * 32 + 2 * vp + 1] = acc1[k];
        }
    }
}

// ---------------- reduce lam_c partials + fold BN + 1/Z ----------------
__global__ __launch_bounds__(256) void klamcred(float* ws) {
    int out = blockIdx.x * 256 + threadIdx.x;   // 0..1023
    if (out >= 1024) return;
    int b = out >> 9, idx = out & 511;
    int kk = idx >> 5, v = idx & 31;
    const float* lamcp = ws + O_LAMCP;
    float S = 0.f;
    for (int c = 0; c < 216; ++c) S += lamcp[((long)b * 216 + c) * 512 + idx];
    float sv = ws[O_SARR + 64 + v], tv = ws[O_TARR + 64 + v];
    ws[O_LAMC + out] = sv * S * ws[O_RZI + b * 16 + kk] + tv;
}

// ---------------- fold q-BN into lam_c: lamc2 = s_q*lam_c, bc = sum t_q*lam_c ----------------
__global__ __launch_bounds__(256) void klamc3(float* ws) {
    int tid = threadIdx.x;
    for (int i = tid; i < 4096; i += 256) {
        int b = i >> 11, r = i & 2047;
        int h = r >> 9, k = (r >> 5) & 15, v = r & 31;
        ws[O_LAMC2 + i] = ws[O_SARR + h * 16 + k] * ws[O_LAMC + b * 512 + k * 32 + v];
    }
    {
        int i = tid;  // 256 threads, 256 outputs
        int b = i >> 7, h = (i >> 5) & 3, v = i & 31;
        float s = 0.f;
#pragma unroll
        for (int k = 0; k < 16; ++k) s += ws[O_TARR + h * 16 + k] * ws[O_LAMC + b * 512 + k * 32 + v];
        ws[O_BC + i] = s;
    }
}

// ---------------- final fused: qw = (BN q)*w reassociation + stencil + y_c ----------------
// tile (d,h,w) = (1,4,16) -> 64 positions; halo (3,6,18) = 324 per v-channel
// y[h,v,n] = bc[h,v] + sum_k qraw[hk,n]*lamc2[h,k,v]
//          + sum_o qw[h,o,n]*vbn[v,n+delta_o],  qw = cw[h,o] + sum_k qraw*sw[h,o,k]
__global__ __launch_bounds__(256, 2) void kfinal(const float* __restrict__ qr, const float* __restrict__ vr,
                                                 const float* __restrict__ ws, float* __restrict__ y) {
    __shared__ float vbn[32 * 324];
    __shared__ float qw[27 * 256];   // [o][h*64 + pos]
    const float* sarr  = ws + O_SARR;
    const float* tarr  = ws + O_TARR;
    const float* swp   = ws + O_SW;
    const float* cwp   = ws + O_CW;
    const float* lamc2 = ws + O_LAMC2;
    const float* bcp   = ws + O_BC;

    int bid = blockIdx.x;                  // 0..3455
    int b = bid / 1728, t = bid - b * 1728;   // tiles: d 48 x h 12 x w 3
    int td = t / 36, r = t - td * 36;
    int th = r / 3, tw = r - th * 3;
    int d0 = td, h0 = th * 4, w0 = tw * 16;
    int tid = threadIdx.x;

    // phase A: halo load of BN'd v (zero pad outside volume, AFTER BN)
    for (int i = tid; i < 32 * 324; i += 256) {
        int v = i / 324, z = i - v * 324;
        int zd = z / 108, rr = z - zd * 108;
        int zh = rr / 18, zw = rr - zh * 18;
        int gd = d0 - 1 + zd, gh = h0 - 1 + zh, gw = w0 - 1 + zw;
        float val = 0.f;
        if ((unsigned)gd < 48u && (unsigned)gh < 48u && (unsigned)gw < 48u) {
            float raw = vr[((long)b * 32 + v) * NPOS + gd * 2304 + gh * 48 + gw];
            val = fmaf(raw, sarr[64 + v], tarr[64 + v]);
        }
        vbn[i] = val;
    }

    // phase B: qw[o][h][pos] for this thread's (h, pos)
    int pos = tid & 63;
    int wv = __builtin_amdgcn_readfirstlane(tid >> 6);   // wave id (h in phase B, v-group in C)
    int lh = pos >> 4, lw = pos & 15;
    int goff = d0 * 2304 + (h0 + lh) * 48 + (w0 + lw);
    {
        float qk[16];
        const float* qbase = qr + ((long)b * 64 + wv * 16) * NPOS + goff;
#pragma unroll
        for (int k = 0; k < 16; ++k) qk[k] = qbase[(long)k * NPOS];
#pragma unroll
        for (int o = 0; o < 27; ++o) {
            float a = cwp[wv * 27 + o];
            const float* swrow = swp + (wv * 27 + o) * 16;
#pragma unroll
            for (int k = 0; k < 16; ++k) a = fmaf(qk[k], swrow[k], a);
            qw[o * 256 + wv * 64 + pos] = a;
        }
    }
    __syncthreads();

    // phase C: this thread handles (pos, v-group wv -> v0..v0+7)
    int v0 = wv * 8;
    float acc[4][8];
#pragma unroll
    for (int hh = 0; hh < 4; ++hh)
#pragma unroll
        for (int vi = 0; vi < 8; ++vi)
            acc[hh][vi] = bcp[(b * 4 + hh) * 32 + v0 + vi];

    // y_c: raw q * s_q-folded lam_c
    const float* qpb = qr + (long)b * 64 * NPOS + goff;
#pragma unroll
    for (int hh = 0; hh < 4; ++hh) {
#pragma unroll
        for (int k = 0; k < 16; ++k) {
            float qv = qpb[(long)(hh * 16 + k) * NPOS];
            const float* l2 = lamc2 + (((b * 4 + hh) * 16 + k) * 32) + v0;
#pragma unroll
            for (int vi = 0; vi < 8; ++vi) acc[hh][vi] = fmaf(qv, l2[vi], acc[hh][vi]);
        }
    }

    // y_p: 27-point stencil with qw
    const float* vb0 = vbn + v0 * 324;
#pragma unroll
    for (int od = 0; od < 3; ++od)
#pragma unroll
    for (int oh = 0; oh < 3; ++oh)
#pragma unroll
    for (int ow = 0; ow < 3; ++ow) {
        int o = od * 9 + oh * 3 + ow;
        float q0 = qw[o * 256 + pos];
        float q1 = qw[o * 256 + 64 + pos];
        float q2 = qw[o * 256 + 128 + pos];
        float q3 = qw[o * 256 + 192 + pos];
        const float* vb = vb0 + od * 108 + (lh + oh) * 18 + (lw + ow);
#pragma unroll
        for (int vi = 0; vi < 8; ++vi) {
            float s = vb[vi * 324];
            acc[0][vi] = fmaf(q0, s, acc[0][vi]);
            acc[1][vi] = fmaf(q1, s, acc[1][vi]);
            acc[2][vi] = fmaf(q2, s, acc[2][vi]);
            acc[3][vi] = fmaf(q3, s, acc[3][vi]);
        }
    }

    long pbase = (long)b * 128 * NPOS + goff;
#pragma unroll
    for (int hh = 0; hh < 4; ++hh)
#pragma unroll
        for (int vi = 0; vi < 8; ++vi)
            y[pbase + (long)(hh * 32 + v0 + vi) * NPOS] = acc[hh][vi];
}

extern "C" void kernel_launch(void* const* d_in, const int* in_sizes, int n_in,
                              void* d_out, int out_size, void* d_ws, size_t ws_size,
                              hipStream_t stream) {
    const float* x    = (const float*)d_in[0];
    const float* Wq   = (const float*)d_in[1];
    const float* Wk   = (const float*)d_in[2];
    const float* Wv   = (const float*)d_in[3];
    const float* Wpos = (const float*)d_in[4];
    const float* gq   = (const float*)d_in[5];
    const float* bq   = (const float*)d_in[6];
    const float* gv   = (const float*)d_in[7];
    const float* bv   = (const float*)d_in[8];
    float* ws = (float*)d_ws;
    float* y  = (float*)d_out;
    float* qr = ws + O_Q;
    float* kr = ws + O_K;
    float* vr = ws + O_V;

    ksetup  <<<58,   256, 0, stream>>>(Wq, Wk, Wv, Wpos, ws);
    kproj   <<<3456, 256, 0, stream>>>(x, ws, qr, kr, vr);
    kstats  <<<768,  256, 0, stream>>>(qr, vr, ws);
    krmaxp  <<<256,  256, 0, stream>>>(kr, ws);
    kfin1   <<<1,    128, 0, stream>>>(gq, bq, gv, bv, ws);
    krzp    <<<256,  256, 0, stream>>>(kr, ws);
    kfin2   <<<1,    256, 0, stream>>>(ws);
    klamcp  <<<432,  256, 0, stream>>>(kr, vr, ws, ws + O_LAMCP);
    klamcred<<<4,    256, 0, stream>>>(ws);
    klamc3  <<<1,    256, 0, stream>>>(ws);
    kfinal  <<<3456, 256, 0, stream>>>(qr, vr, ws, y);
}

// Round 4
// 328.397 us; speedup vs baseline: 1.5897x; 1.1340x over previous
//
#include <hip/hip_runtime.h>
#include <math.h>

#define NPOS 110592   // 48*48*48
#define EPS 1e-5f

// workspace layout (float element offsets)
constexpr long O_WT    = 0;          // 112*128 = 14336  (WT[c][oc], oc: 0..63 q, 64..79 k, 80..111 v)
constexpr long O_WPT   = 14336;      // 27*16 = 432      (wposT[o][k])
constexpr long O_SARR  = 14768;      // 96  (scale: 0..63 q, 64..95 v)
constexpr long O_TARR  = 14864;      // 96  (shift)
constexpr long O_STPS  = 14960;      // 96*8 sum partials
constexpr long O_STPQ  = 15728;      // 96*8 sumsq partials
constexpr long O_RMP   = 16496;      // 32*8 rowmax partials
constexpr long O_RMAX  = 16752;      // 32
constexpr long O_RZP   = 16784;      // 32*8 rowsum partials
constexpr long O_RZI   = 17040;      // 32 (1/Z)
constexpr long O_LAMC  = 17072;      // 2*16*32 = 1024
constexpr long O_LAMCP = 18096;      // 2*216*512 = 221184
constexpr long O_SW    = 239280;     // 4*27*16 = 1728   (s_q-folded conv weights)
constexpr long O_CW    = 241008;     // 108 (+pad)       (t_q-folded conv bias)
constexpr long O_LAMC2 = 241120;     // 2*4*16*32 = 4096 (s_q-folded lam_c)
constexpr long O_BC    = 245216;     // 2*4*32 = 256     (t_q-folded lam_c bias)
constexpr long O_Q     = 460464;     // 2*64*NPOS = 14155776
constexpr long O_K     = 14616240;   // 2*16*NPOS = 3538944
constexpr long O_V     = 18155184;   // 2*32*NPOS = 7077888
// total 25233072 floats = 100.9 MB (unchanged)

// ---------------- setup: transpose weights ----------------
__global__ __launch_bounds__(256) void ksetup(const float* Wq, const float* Wk, const float* Wv,
                                              const float* Wpos, float* ws) {
    int i = blockIdx.x * 256 + threadIdx.x;
    if (i < 14336) {
        int c = i / 112, oc = i - c * 112;
        float v;
        if (oc < 64)       v = Wq[oc * 128 + c];
        else if (oc < 80)  v = Wk[(oc - 64) * 128 + c];
        else               v = Wv[(oc - 80) * 128 + c];
        ws[O_WT + i] = v;
    } else if (i < 14336 + 432) {
        int j = i - 14336;
        int o = j >> 4, k = j & 15;
        ws[O_WPT + j] = Wpos[k * 27 + o];   // Wpos[k][0][od][oh][ow], o = od*9+oh*3+ow
    }
}

// ---------------- projection: q_raw/k_raw/v_raw = W * x ----------------
__global__ __launch_bounds__(256) void kproj(const float* __restrict__ x, const float* __restrict__ ws,
                                             float* __restrict__ qr, float* __restrict__ kr,
                                             float* __restrict__ vr) {
    __shared__ float xs[128 * 64];
    const float* WT = ws + O_WT;
    int blk = blockIdx.x;                 // 0..3455
    int b = blk / 1728, tile = blk - b * 1728;
    long base = (long)b * 128 * NPOS + (long)tile * 64;
    int tid = threadIdx.x;
    for (int i = tid; i < 128 * 64; i += 256) {
        int c = i >> 6, p = i & 63;
        xs[c * 64 + p] = x[base + (long)c * NPOS + p];
    }
    __syncthreads();
    int lane = tid & 63;
    int w = __builtin_amdgcn_readfirstlane(tid >> 6);   // wave id, provably uniform
    float acc[28];
#pragma unroll
    for (int i = 0; i < 28; ++i) acc[i] = 0.f;
    const float* wrow = WT + w * 28;
#pragma unroll 4
    for (int c = 0; c < 128; ++c) {
        float xv = xs[c * 64 + lane];
#pragma unroll
        for (int i = 0; i < 28; ++i) acc[i] = fmaf(wrow[c * 112 + i], xv, acc[i]);
    }
    int pos = tile * 64 + lane;
#pragma unroll
    for (int i = 0; i < 28; ++i) {
        int oc = w * 28 + i;
        float val = acc[i];
        if (oc < 64)      qr[((long)b * 64 + oc) * NPOS + pos] = val;
        else if (oc < 80) kr[((long)b * 16 + (oc - 64)) * NPOS + pos] = val;
        else              vr[((long)b * 32 + (oc - 80)) * NPOS + pos] = val;
    }
}

// ---------------- BN stat partials (96 channels x 8 slabs) ----------------
__global__ __launch_bounds__(256) void kstats(const float* __restrict__ qr, const float* __restrict__ vr,
                                              float* __restrict__ ws) {
    __shared__ float red[256], red2[256];
    int ch = blockIdx.x >> 3, slab = blockIdx.x & 7;
    int b = slab >> 2;
    int p0 = (slab & 3) * 27648;
    const float* src = (ch < 64) ? qr + ((long)b * 64 + ch) * NPOS
                                 : vr + ((long)b * 32 + (ch - 64)) * NPOS;
    const float4* src4 = (const float4*)(src + p0);
    float s = 0.f, q = 0.f;
    for (int i = threadIdx.x; i < 6912; i += 256) {
        float4 v = src4[i];
        s += v.x + v.y + v.z + v.w;
        q = fmaf(v.x, v.x, q); q = fmaf(v.y, v.y, q);
        q = fmaf(v.z, v.z, q); q = fmaf(v.w, v.w, q);
    }
    red[threadIdx.x] = s; red2[threadIdx.x] = q;
    __syncthreads();
    for (int st = 128; st > 0; st >>= 1) {
        if (threadIdx.x < st) { red[threadIdx.x] += red[threadIdx.x + st]; red2[threadIdx.x] += red2[threadIdx.x + st]; }
        __syncthreads();
    }
    if (threadIdx.x == 0) {
        ws[O_STPS + ch * 8 + slab] = red[0];
        ws[O_STPQ + ch * 8 + slab] = red2[0];
    }
}

// ---------------- softmax rowmax partials (32 rows x 8 slabs) ----------------
__global__ __launch_bounds__(256) void krmaxp(const float* __restrict__ kr, float* __restrict__ ws) {
    __shared__ float red[256];
    int row = blockIdx.x >> 3, slab = blockIdx.x & 7;
    int b = row >> 4, kk = row & 15;
    const float4* src = (const float4*)(kr + ((long)b * 16 + kk) * NPOS + slab * 13824);
    float m = -1e30f;
    for (int i = threadIdx.x; i < 3456; i += 256) {
        float4 v = src[i];
        m = fmaxf(m, fmaxf(fmaxf(v.x, v.y), fmaxf(v.z, v.w)));
    }
    red[threadIdx.x] = m;
    __syncthreads();
    for (int st = 128; st > 0; st >>= 1) {
        if (threadIdx.x < st) red[threadIdx.x] = fmaxf(red[threadIdx.x], red[threadIdx.x + st]);
        __syncthreads();
    }
    if (threadIdx.x == 0) ws[O_RMP + row * 8 + slab] = red[0];
}

// ---------------- finalize BN stats + rowmax ----------------
__global__ __launch_bounds__(128) void kfin1(const float* gq, const float* bq, const float* gv,
                                             const float* bv, float* ws) {
    int tid = threadIdx.x;
    if (tid < 96) {
        float s = 0.f, q = 0.f;
        for (int j = 0; j < 8; ++j) { s += ws[O_STPS + tid * 8 + j]; q += ws[O_STPQ + tid * 8 + j]; }
        const float inv_n = 1.f / 221184.f;
        float mean = s * inv_n;
        float var = q * inv_n - mean * mean;
        float g, bb;
        if (tid < 64) { g = gq[tid]; bb = bq[tid]; }
        else          { g = gv[tid - 64]; bb = bv[tid - 64]; }
        float sc = g * rsqrtf(var + EPS);
        ws[O_SARR + tid] = sc;
        ws[O_TARR + tid] = bb - mean * sc;
    } else if (tid < 128) {
        int row = tid - 96;
        float m = -1e30f;
        for (int j = 0; j < 8; ++j) m = fmaxf(m, ws[O_RMP + row * 8 + j]);
        ws[O_RMAX + row] = m;
    }
}

// ---------------- softmax denom partials ----------------
__global__ __launch_bounds__(256) void krzp(const float* __restrict__ kr, float* __restrict__ ws) {
    __shared__ float red[256];
    int row = blockIdx.x >> 3, slab = blockIdx.x & 7;
    int b = row >> 4, kk = row & 15;
    float rmax = ws[O_RMAX + row];
    const float4* src = (const float4*)(kr + ((long)b * 16 + kk) * NPOS + slab * 13824);
    float s = 0.f;
    for (int i = threadIdx.x; i < 3456; i += 256) {
        float4 v = src[i];
        s += expf(v.x - rmax) + expf(v.y - rmax) + expf(v.z - rmax) + expf(v.w - rmax);
    }
    red[threadIdx.x] = s;
    __syncthreads();
    for (int st = 128; st > 0; st >>= 1) {
        if (threadIdx.x < st) red[threadIdx.x] += red[threadIdx.x + st];
        __syncthreads();
    }
    if (threadIdx.x == 0) ws[O_RZP + row * 8 + slab] = red[0];
}

// ---------------- finalize Z, fold BN into conv weights ----------------
__global__ __launch_bounds__(256) void kfin2(float* ws) {
    int tid = threadIdx.x;
    if (tid < 32) {
        float s = 0.f;
        for (int j = 0; j < 8; ++j) s += ws[O_RZP + tid * 8 + j];
        ws[O_RZI + tid] = 1.f / s;
    }
    // sw[h][o][k] = s_q[h*16+k] * w[o][k]
    for (int i = tid; i < 1728; i += 256) {
        int h = i / 432, r = i - h * 432, o = r >> 4, k = r & 15;
        ws[O_SW + i] = ws[O_SARR + h * 16 + k] * ws[O_WPT + o * 16 + k];
    }
    // cw[h][o] = sum_k t_q[h*16+k] * w[o][k]
    if (tid < 108) {
        int h = tid / 27, o = tid - h * 27;
        float s = 0.f;
        for (int k = 0; k < 16; ++k) s += ws[O_TARR + h * 16 + k] * ws[O_WPT + o * 16 + k];
        ws[O_CW + tid] = s;
    }
}

// ---------------- lam_c partials: S[k][v] = sum_p e[k][p] * v_raw[v][p] ----------------
__global__ __launch_bounds__(256) void klamcp(const float* __restrict__ kr, const float* __restrict__ vr,
                                              const float* __restrict__ ws, float* __restrict__ lamcp) {
    __shared__ float es[16 * 512];
    const float* rmax = ws + O_RMAX;
    int bid = blockIdx.x;                  // 0..431
    int b = bid / 216, chunk = bid - b * 216;
    long p0 = (long)chunk * 512;
    int tid = threadIdx.x;
    for (int i = tid; i < 16 * 512; i += 256) {
        int r = i >> 9, p = i & 511;
        es[i] = expf(kr[((long)b * 16 + r) * NPOS + p0 + p] - rmax[b * 16 + r]);
    }
    __syncthreads();
    int vp = tid >> 4, pl = tid & 15;      // v-pair 0..15, position lane 0..15
    const float* v0p = vr + ((long)b * 32 + 2 * vp) * NPOS + p0;
    const float* v1p = v0p + NPOS;
    float acc0[16], acc1[16];
#pragma unroll
    for (int k = 0; k < 16; ++k) { acc0[k] = 0.f; acc1[k] = 0.f; }
    for (int j = 0; j < 32; ++j) {
        int p = pl + 16 * j;
        float v0 = v0p[p], v1 = v1p[p];
#pragma unroll
        for (int k = 0; k < 16; ++k) {
            float e = es[k * 512 + p];
            acc0[k] = fmaf(e, v0, acc0[k]);
            acc1[k] = fmaf(e, v1, acc1[k]);
        }
    }
    // reduce across the 16 position-lanes of each v-pair group
#pragma unroll
    for (int m = 1; m < 16; m <<= 1) {
#pragma unroll
        for (int k = 0; k < 16; ++k) {
            acc0[k] += __shfl_xor(acc0[k], m, 64);
            acc1[k] += __shfl_xor(acc1[k], m, 64);
        }
    }
    if (pl == 0) {
        long base = (long)bid * 512;
#pragma unroll
        for (int k = 0; k < 16; ++k) {
            lamcp[base + k * 32 + 2 * vp]     = acc0[k];
            lamcp[base + k * 32 + 2 * vp + 1] = acc1[k];
        }
    }
}

// ---------------- reduce lam_c partials + fold BN + 1/Z ----------------
__global__ __launch_bounds__(256) void klamcred(float* ws) {
    int out = blockIdx.x * 256 + threadIdx.x;   // 0..1023
    if (out >= 1024) return;
    int b = out >> 9, idx = out & 511;
    int kk = idx >> 5, v = idx & 31;
    const float* lamcp = ws + O_LAMCP;
    float S = 0.f;
    for (int c = 0; c < 216; ++c) S += lamcp[((long)b * 216 + c) * 512 + idx];
    float sv = ws[O_SARR + 64 + v], tv = ws[O_TARR + 64 + v];
    ws[O_LAMC + out] = sv * S * ws[O_RZI + b * 16 + kk] + tv;
}

// ---------------- fold q-BN into lam_c: lamc2 = s_q*lam_c, bc = sum t_q*lam_c ----------------
__global__ __launch_bounds__(256) void klamc3(float* ws) {
    int tid = threadIdx.x;
    for (int i = tid; i < 4096; i += 256) {
        int b = i >> 11, r = i & 2047;
        int h = r >> 9, k = (r >> 5) & 15, v = r & 31;
        ws[O_LAMC2 + i] = ws[O_SARR + h * 16 + k] * ws[O_LAMC + b * 512 + k * 32 + v];
    }
    {
        int i = tid;  // 256 threads, 256 outputs
        int b = i >> 7, h = (i >> 5) & 3, v = i & 31;
        float s = 0.f;
#pragma unroll
        for (int k = 0; k < 16; ++k) s += ws[O_TARR + h * 16 + k] * ws[O_LAMC + b * 512 + k * 32 + v];
        ws[O_BC + i] = s;
    }
}

// ---------------- final fused: qw reassociation + swizzled-vbn stencil + y_c ----------------
// tile (d,h,w) = (1,4,16) -> 64 positions; halo (3,6,18) -> z = 0..323 per v-channel
// vbn layout: [z][v0..31], 16B-slot XOR swizzle: float idx = z*32 + ((v>>2 ^ (z&7))<<2) + (v&3)
// y[h,v,n] = bc[h,v] + sum_k qraw[hk,n]*lamc2[h,k,v]
//          + sum_o qw[h,o,n]*vbn[n+delta_o][v],  qw = cw[h,o] + sum_k qraw*sw[h,o,k]
__global__ __launch_bounds__(256, 2) void kfinal(const float* __restrict__ qr, const float* __restrict__ vr,
                                                 const float* __restrict__ ws, float* __restrict__ y) {
    __shared__ float4 vbn4[324 * 8];   // 41472 B, [z][8 slots of 4 v] swizzled
    __shared__ float qw[27 * 256];     // [o][h*64 + pos], 27648 B
    const float* sarr  = ws + O_SARR;
    const float* tarr  = ws + O_TARR;
    const float* swp   = ws + O_SW;
    const float* cwp   = ws + O_CW;
    const float* lamc2 = ws + O_LAMC2;
    const float* bcp   = ws + O_BC;

    int bid = blockIdx.x;                  // 0..3455
    int b = bid / 1728, t = bid - b * 1728;   // tiles: d 48 x h 12 x w 3
    int td = t / 36, r = t - td * 36;
    int th = r / 3, tw = r - th * 3;
    int d0 = td, h0 = th * 4, w0 = tw * 16;
    int tid = threadIdx.x;

    // phase A: halo load of BN'd v (zero pad outside volume, AFTER BN), v-pair per thread
    {
        float2* vbn2 = (float2*)vbn4;
        for (int i = tid; i < 16 * 324; i += 256) {
            int vp = i / 324, z = i - vp * 324;       // vp: v-pair 0..15 (v = 2*vp)
            int zd = z / 108, rr = z - zd * 108;
            int zh = rr / 18, zw = rr - zh * 18;
            int gd = d0 - 1 + zd, gh = h0 - 1 + zh, gw = w0 - 1 + zw;
            float a = 0.f, c = 0.f;
            if ((unsigned)gd < 48u && (unsigned)gh < 48u && (unsigned)gw < 48u) {
                long gidx = ((long)b * 32 + 2 * vp) * NPOS + gd * 2304 + gh * 48 + gw;
                a = fmaf(vr[gidx], sarr[64 + 2 * vp], tarr[64 + 2 * vp]);
                c = fmaf(vr[gidx + NPOS], sarr[65 + 2 * vp], tarr[65 + 2 * vp]);
            }
            // float2 index: z*16 + ((vp>>1 ^ (z&7))<<1) + (vp&1)
            vbn2[z * 16 + ((((vp >> 1) ^ (z & 7))) << 1) + (vp & 1)] = make_float2(a, c);
        }
    }

    // phase B: qw[o][h][pos] for this thread's (h, pos)
    int pos = tid & 63;
    int wv = __builtin_amdgcn_readfirstlane(tid >> 6);   // wave id (h in phase B, v-group in C)
    int lh = pos >> 4, lw = pos & 15;
    int goff = d0 * 2304 + (h0 + lh) * 48 + (w0 + lw);
    {
        float qk[16];
        const float* qbase = qr + ((long)b * 64 + wv * 16) * NPOS + goff;
#pragma unroll
        for (int k = 0; k < 16; ++k) qk[k] = qbase[(long)k * NPOS];
#pragma unroll
        for (int o = 0; o < 27; ++o) {
            float a = cwp[wv * 27 + o];
            const float* swrow = swp + (wv * 27 + o) * 16;
#pragma unroll
            for (int k = 0; k < 16; ++k) a = fmaf(qk[k], swrow[k], a);
            qw[o * 256 + wv * 64 + pos] = a;
        }
    }
    __syncthreads();

    // phase C: this thread handles (pos, v-group wv -> v0..v0+7)
    int v0 = wv * 8;
    float acc[4][8];
#pragma unroll
    for (int hh = 0; hh < 4; ++hh)
#pragma unroll
        for (int vi = 0; vi < 8; ++vi)
            acc[hh][vi] = bcp[(b * 4 + hh) * 32 + v0 + vi];

    // y_c: raw q * s_q-folded lam_c (lamc2/bc are wave-uniform -> scalar loads)
    const float* qpb = qr + (long)b * 64 * NPOS + goff;
#pragma unroll
    for (int hh = 0; hh < 4; ++hh) {
#pragma unroll
        for (int k = 0; k < 16; ++k) {
            float qv = qpb[(long)(hh * 16 + k) * NPOS];
            const float* l2 = lamc2 + (((b * 4 + hh) * 16 + k) * 32) + v0;
#pragma unroll
            for (int vi = 0; vi < 8; ++vi) acc[hh][vi] = fmaf(qv, l2[vi], acc[hh][vi]);
        }
    }

    // y_p: 27-point stencil, vbn via 2x ds_read_b128 per point (swizzle-matched)
    int zb = lh * 18 + lw;
    int slotA = 2 * wv, slotB = 2 * wv + 1;
#pragma unroll
    for (int od = 0; od < 3; ++od)
#pragma unroll
    for (int oh = 0; oh < 3; ++oh)
#pragma unroll
    for (int ow = 0; ow < 3; ++ow) {
        int o = od * 9 + oh * 3 + ow;
        int z = zb + od * 108 + oh * 18 + ow;
        int zs = z & 7;
        float4 sA = vbn4[z * 8 + (slotA ^ zs)];
        float4 sB = vbn4[z * 8 + (slotB ^ zs)];
        float q0 = qw[o * 256 + pos];
        float q1 = qw[o * 256 + 64 + pos];
        float q2 = qw[o * 256 + 128 + pos];
        float q3 = qw[o * 256 + 192 + pos];
        acc[0][0] = fmaf(q0, sA.x, acc[0][0]); acc[0][1] = fmaf(q0, sA.y, acc[0][1]);
        acc[0][2] = fmaf(q0, sA.z, acc[0][2]); acc[0][3] = fmaf(q0, sA.w, acc[0][3]);
        acc[0][4] = fmaf(q0, sB.x, acc[0][4]); acc[0][5] = fmaf(q0, sB.y, acc[0][5]);
        acc[0][6] = fmaf(q0, sB.z, acc[0][6]); acc[0][7] = fmaf(q0, sB.w, acc[0][7]);
        acc[1][0] = fmaf(q1, sA.x, acc[1][0]); acc[1][1] = fmaf(q1, sA.y, acc[1][1]);
        acc[1][2] = fmaf(q1, sA.z, acc[1][2]); acc[1][3] = fmaf(q1, sA.w, acc[1][3]);
        acc[1][4] = fmaf(q1, sB.x, acc[1][4]); acc[1][5] = fmaf(q1, sB.y, acc[1][5]);
        acc[1][6] = fmaf(q1, sB.z, acc[1][6]); acc[1][7] = fmaf(q1, sB.w, acc[1][7]);
        acc[2][0] = fmaf(q2, sA.x, acc[2][0]); acc[2][1] = fmaf(q2, sA.y, acc[2][1]);
        acc[2][2] = fmaf(q2, sA.z, acc[2][2]); acc[2][3] = fmaf(q2, sA.w, acc[2][3]);
        acc[2][4] = fmaf(q2, sB.x, acc[2][4]); acc[2][5] = fmaf(q2, sB.y, acc[2][5]);
        acc[2][6] = fmaf(q2, sB.z, acc[2][6]); acc[2][7] = fmaf(q2, sB.w, acc[2][7]);
        acc[3][0] = fmaf(q3, sA.x, acc[3][0]); acc[3][1] = fmaf(q3, sA.y, acc[3][1]);
        acc[3][2] = fmaf(q3, sA.z, acc[3][2]); acc[3][3] = fmaf(q3, sA.w, acc[3][3]);
        acc[3][4] = fmaf(q3, sB.x, acc[3][4]); acc[3][5] = fmaf(q3, sB.y, acc[3][5]);
        acc[3][6] = fmaf(q3, sB.z, acc[3][6]); acc[3][7] = fmaf(q3, sB.w, acc[3][7]);
    }

    long pbase = (long)b * 128 * NPOS + goff;
#pragma unroll
    for (int hh = 0; hh < 4; ++hh)
#pragma unroll
        for (int vi = 0; vi < 8; ++vi)
            y[pbase + (long)(hh * 32 + v0 + vi) * NPOS] = acc[hh][vi];
}

extern "C" void kernel_launch(void* const* d_in, const int* in_sizes, int n_in,
                              void* d_out, int out_size, void* d_ws, size_t ws_size,
                              hipStream_t stream) {
    const float* x    = (const float*)d_in[0];
    const float* Wq   = (const float*)d_in[1];
    const float* Wk   = (const float*)d_in[2];
    const float* Wv   = (const float*)d_in[3];
    const float* Wpos = (const float*)d_in[4];
    const float* gq   = (const float*)d_in[5];
    const float* bq   = (const float*)d_in[6];
    const float* gv   = (const float*)d_in[7];
    const float* bv   = (const float*)d_in[8];
    float* ws = (float*)d_ws;
    float* y  = (float*)d_out;
    float* qr = ws + O_Q;
    float* kr = ws + O_K;
    float* vr = ws + O_V;

    ksetup  <<<58,   256, 0, stream>>>(Wq, Wk, Wv, Wpos, ws);
    kproj   <<<3456, 256, 0, stream>>>(x, ws, qr, kr, vr);
    kstats  <<<768,  256, 0, stream>>>(qr, vr, ws);
    krmaxp  <<<256,  256, 0, stream>>>(kr, ws);
    kfin1   <<<1,    128, 0, stream>>>(gq, bq, gv, bv, ws);
    krzp    <<<256,  256, 0, stream>>>(kr, ws);
    kfin2   <<<1,    256, 0, stream>>>(ws);
    klamcp  <<<432,  256, 0, stream>>>(kr, vr, ws, ws + O_LAMCP);
    klamcred<<<4,    256, 0, stream>>>(ws);
    klamc3  <<<1,    256, 0, stream>>>(ws);
    kfinal  <<<3456, 256, 0, stream>>>(qr, vr, ws, y);
}

// Round 5
// 277.003 us; speedup vs baseline: 1.8846x; 1.1855x over previous
//
#include <hip/hip_runtime.h>
#include <math.h>

#define NPOS 110592   // 48*48*48
#define EPS 1e-5f

using bf16x8 = __attribute__((ext_vector_type(8))) short;
using f32x4  = __attribute__((ext_vector_type(4))) float;

// ws layout (float element offsets)
constexpr long O_WB    = 0;        // 112x128 bf16 = 7168 floats (W[oc][c])
constexpr long O_WPT   = 7168;     // 27*16 fp32 (wposT[o][k])
constexpr long O_SARR  = 7600;     // 96  (BN scale: 0..63 q, 64..95 v)
constexpr long O_TARR  = 7696;     // 96  (BN shift)
constexpr long O_RMAX  = 7792;     // 32  (softmax rowmax per (b,k))
constexpr long O_ZP    = 7824;     // 432*16 softmax denom partials
constexpr long O_RZI   = 14736;    // 32 (1/Z)
constexpr long O_SW    = 14768;    // 4*27*16 (s_q-folded conv weights)
constexpr long O_CW    = 16496;    // 108(+pad) (t_q-folded conv bias)
constexpr long O_LAMC  = 16608;    // 2*16*32
constexpr long O_LAMC2 = 17632;    // 2*4*16*32 (s_q-folded lam_c)
constexpr long O_BC    = 21728;    // 2*4*32 (t_q-folded lam_c bias)
constexpr long O_LAMCP = 21984;    // 2*216*512 lam_c partials
constexpr long O_Q     = 243168;   // 2*64*NPOS
constexpr long O_K     = 14398944; // 2*16*NPOS
constexpr long O_V     = 17937888; // 2*32*NPOS
// total 25015776 floats = 100.1 MB

__device__ inline unsigned short f2bf(float f) {
    unsigned int u = __float_as_uint(f);
    u += 0x7FFFu + ((u >> 16) & 1u);   // RNE
    return (unsigned short)(u >> 16);
}
__device__ inline float bflo(unsigned int u) { return __uint_as_float(u << 16); }
__device__ inline float bfhi(unsigned int u) { return __uint_as_float(u & 0xFFFF0000u); }

// ---------------- setup: bf16 weights [oc][c] + wposT ----------------
__global__ __launch_bounds__(256) void ksetup(const float* Wq, const float* Wk, const float* Wv,
                                              const float* Wpos, float* ws) {
    int i = blockIdx.x * 256 + threadIdx.x;
    if (i < 7168) {
        int oc = i >> 6, cp = i & 63;
        int c = 2 * cp;
        float v0, v1;
        if (oc < 64)      { v0 = Wq[oc * 128 + c];        v1 = Wq[oc * 128 + c + 1]; }
        else if (oc < 80) { v0 = Wk[(oc - 64) * 128 + c]; v1 = Wk[(oc - 64) * 128 + c + 1]; }
        else              { v0 = Wv[(oc - 80) * 128 + c]; v1 = Wv[(oc - 80) * 128 + c + 1]; }
        ((unsigned int*)(ws + O_WB))[i] = (unsigned int)f2bf(v0) | ((unsigned int)f2bf(v1) << 16);
    } else if (i < 7600) {
        int j = i - 7168;
        int o = j >> 4, k = j & 15;
        ws[O_WPT + j] = Wpos[k * 27 + o];   // o = od*9+oh*3+ow
    }
}

// ---------------- projection via MFMA + fused stat partials ----------------
// block = 4 waves, 64 positions; wave wv owns pos chunk wv*16..+15, all 7 oc-tiles
__global__ __launch_bounds__(256, 4) void kproj(const float* __restrict__ x, const float* __restrict__ ws,
                                                float* __restrict__ qr, float* __restrict__ kr,
                                                float* __restrict__ vr,
                                                float* __restrict__ PS, float* __restrict__ PQ,
                                                float* __restrict__ PM) {
    __shared__ unsigned int xsu[64 * 68];   // [pos][c] bf16, row = 136 ushort = 272 B
    __shared__ float pss[4 * 112], psq[4 * 112], pmx[4 * 16];
    const unsigned short* WBu = (const unsigned short*)(ws + O_WB);

    int blk = blockIdx.x;                 // 0..3455
    int b = blk / 1728, tile = blk - b * 1728;
    long base = (long)b * 128 * NPOS + (long)tile * 64;
    int tid = threadIdx.x;

    // stage x tile transposed to [pos][c] bf16
    for (int i = tid; i < 64 * 64; i += 256) {
        int cp = i >> 6, p = i & 63;      // c-pair, position
        float v0 = x[base + (long)(2 * cp) * NPOS + p];
        float v1 = x[base + (long)(2 * cp + 1) * NPOS + p];
        xsu[p * 68 + cp] = (unsigned int)f2bf(v0) | ((unsigned int)f2bf(v1) << 16);
    }
    __syncthreads();

    int lane = tid & 63;
    int wv = __builtin_amdgcn_readfirstlane(tid >> 6);
    int r = lane & 15, g = lane >> 4;

    f32x4 acc[7];
#pragma unroll
    for (int t = 0; t < 7; ++t) acc[t] = (f32x4){0.f, 0.f, 0.f, 0.f};

    const unsigned short* xrow = (const unsigned short*)xsu + (wv * 16 + r) * 136;
#pragma unroll
    for (int ks = 0; ks < 4; ++ks) {
        bf16x8 bfrag = *(const bf16x8*)(const void*)(xrow + ks * 32 + g * 8);
#pragma unroll
        for (int t = 0; t < 7; ++t) {
            bf16x8 afrag = *(const bf16x8*)(const void*)(WBu + (t * 16 + r) * 128 + ks * 32 + g * 8);
            acc[t] = __builtin_amdgcn_mfma_f32_16x16x32_bf16(afrag, bfrag, acc[t], 0, 0, 0);
        }
    }

    // store q/k/v (C layout: col=lane&15 -> pos, row=g*4+j -> oc-in-tile)
    long pos = (long)tile * 64 + wv * 16 + r;
#pragma unroll
    for (int t = 0; t < 7; ++t) {
#pragma unroll
        for (int j = 0; j < 4; ++j) {
            int oc = t * 16 + g * 4 + j;
            float val = acc[t][j];
            if (t < 4)       qr[((long)b * 64 + oc) * NPOS + pos] = val;
            else if (t == 4) kr[((long)b * 16 + (oc - 64)) * NPOS + pos] = val;
            else             vr[((long)b * 32 + (oc - 80)) * NPOS + pos] = val;
        }
    }

    // fused stat partials: sum/sumsq per oc over this block's 64 pos; max for k rows
#pragma unroll
    for (int t = 0; t < 7; ++t) {
#pragma unroll
        for (int j = 0; j < 4; ++j) {
            float s = acc[t][j];
            float q = s * s;
#pragma unroll
            for (int m = 1; m < 16; m <<= 1) {
                s += __shfl_xor(s, m, 64);
                q += __shfl_xor(q, m, 64);
            }
            if (r == 0) {
                int oc = t * 16 + g * 4 + j;
                pss[wv * 112 + oc] = s;
                psq[wv * 112 + oc] = q;
            }
        }
    }
#pragma unroll
    for (int j = 0; j < 4; ++j) {
        float m = acc[4][j];
#pragma unroll
        for (int mm = 1; mm < 16; mm <<= 1) m = fmaxf(m, __shfl_xor(m, mm, 64));
        if (r == 0) pmx[wv * 16 + g * 4 + j] = m;
    }
    __syncthreads();
    if (tid < 112) {
        float s = pss[tid] + pss[112 + tid] + pss[224 + tid] + pss[336 + tid];
        float q = psq[tid] + psq[112 + tid] + psq[224 + tid] + psq[336 + tid];
        PS[(long)blk * 112 + tid] = s;
        PQ[(long)blk * 112 + tid] = q;
    } else if (tid < 128) {
        int kk = tid - 112;
        PM[(long)blk * 16 + kk] = fmaxf(fmaxf(pmx[kk], pmx[16 + kk]),
                                        fmaxf(pmx[32 + kk], pmx[48 + kk]));
    }
}

// ---------------- reduce partials: BN scale/shift + k rowmax ----------------
__global__ __launch_bounds__(256) void kred(const float* __restrict__ PS, const float* __restrict__ PQ,
                                            const float* __restrict__ PM,
                                            const float* gq, const float* bq,
                                            const float* gv, const float* bv, float* ws) {
    __shared__ float rs[256], rq[256];
    int bid = blockIdx.x, tid = threadIdx.x;
    if (bid < 96) {
        int c = bid;
        int oc = c < 64 ? c : c + 16;
        float s = 0.f, q = 0.f;
        for (int i = tid; i < 3456; i += 256) {
            s += PS[(long)i * 112 + oc];
            q += PQ[(long)i * 112 + oc];
        }
        rs[tid] = s; rq[tid] = q;
        __syncthreads();
        for (int st = 128; st > 0; st >>= 1) {
            if (tid < st) { rs[tid] += rs[tid + st]; rq[tid] += rq[tid + st]; }
            __syncthreads();
        }
        if (tid == 0) {
            const float inv_n = 1.f / 221184.f;
            float mean = rs[0] * inv_n;
            float var = rq[0] * inv_n - mean * mean;
            float g = c < 64 ? gq[c] : gv[c - 64];
            float bb = c < 64 ? bq[c] : bv[c - 64];
            float sc = g * rsqrtf(var + EPS);
            ws[O_SARR + c] = sc;
            ws[O_TARR + c] = bb - mean * sc;
        }
    } else {
        int row = bid - 96;                 // 0..31 = b*16+kk
        int b = row >> 4, kk = row & 15;
        float m = -1e30f;
        for (int i = tid; i < 1728; i += 256) m = fmaxf(m, PM[((long)b * 1728 + i) * 16 + kk]);
        rs[tid] = m;
        __syncthreads();
        for (int st = 128; st > 0; st >>= 1) {
            if (tid < st) rs[tid] = fmaxf(rs[tid], rs[tid + st]);
            __syncthreads();
        }
        if (tid == 0) ws[O_RMAX + row] = rs[0];
    }
}

// ---------------- lam_c partials + softmax Z partials ----------------
__global__ __launch_bounds__(256) void klamcp(const float* __restrict__ kr, const float* __restrict__ vr,
                                              float* __restrict__ ws, float* __restrict__ lamcp) {
    __shared__ float es[16 * 512];
    const float* rmax = ws + O_RMAX;
    int bid = blockIdx.x;                  // 0..431
    int b = bid / 216, chunk = bid - b * 216;
    long p0 = (long)chunk * 512;
    int tid = threadIdx.x;
    for (int i = tid; i < 16 * 512; i += 256) {
        int rr = i >> 9, p = i & 511;
        es[i] = expf(kr[((long)b * 16 + rr) * NPOS + p0 + p] - rmax[b * 16 + rr]);
    }
    __syncthreads();
    int vp = tid >> 4, pl = tid & 15;      // v-pair 0..15, position lane 0..15
    const float* v0p = vr + ((long)b * 32 + 2 * vp) * NPOS + p0;
    const float* v1p = v0p + NPOS;
    float acc0[16], acc1[16];
#pragma unroll
    for (int k = 0; k < 16; ++k) { acc0[k] = 0.f; acc1[k] = 0.f; }
    for (int j = 0; j < 32; ++j) {
        int p = pl + 16 * j;
        float v0 = v0p[p], v1 = v1p[p];
#pragma unroll
        for (int k = 0; k < 16; ++k) {
            float e = es[k * 512 + p];
            acc0[k] = fmaf(e, v0, acc0[k]);
            acc1[k] = fmaf(e, v1, acc1[k]);
        }
    }
#pragma unroll
    for (int m = 1; m < 16; m <<= 1) {
#pragma unroll
        for (int k = 0; k < 16; ++k) {
            acc0[k] += __shfl_xor(acc0[k], m, 64);
            acc1[k] += __shfl_xor(acc1[k], m, 64);
        }
    }
    if (pl == 0) {
        long base = (long)bid * 512;
#pragma unroll
        for (int k = 0; k < 16; ++k) {
            lamcp[base + k * 32 + 2 * vp]     = acc0[k];
            lamcp[base + k * 32 + 2 * vp + 1] = acc1[k];
        }
    }
    // softmax denom partials from es
    {
        int rr = tid >> 4, j = tid & 15;
        float s = 0.f;
        const float* er = es + rr * 512 + j * 32;
#pragma unroll 8
        for (int i = 0; i < 32; ++i) s += er[i];
#pragma unroll
        for (int m = 1; m < 16; m <<= 1) s += __shfl_xor(s, m, 64);
        if (j == 0) ws[O_ZP + (long)bid * 16 + rr] = s;
    }
}

// ---------------- finalize Z, fold BN into conv weights ----------------
__global__ __launch_bounds__(256) void kfin2(float* ws) {
    int tid = threadIdx.x;
    if (tid < 32) {
        int b = tid >> 4, kk = tid & 15;
        float s = 0.f;
        for (int c = 0; c < 216; ++c) s += ws[O_ZP + ((long)b * 216 + c) * 16 + kk];
        ws[O_RZI + tid] = 1.f / s;
    }
    for (int i = tid; i < 1728; i += 256) {
        int h = i / 432, r = i - h * 432, o = r >> 4, k = r & 15;
        ws[O_SW + i] = ws[O_SARR + h * 16 + k] * ws[O_WPT + o * 16 + k];
    }
    if (tid < 108) {
        int h = tid / 27, o = tid - h * 27;
        float s = 0.f;
        for (int k = 0; k < 16; ++k) s += ws[O_TARR + h * 16 + k] * ws[O_WPT + o * 16 + k];
        ws[O_CW + tid] = s;
    }
}

// ---------------- reduce lam_c partials + fold BN + 1/Z ----------------
__global__ __launch_bounds__(256) void klamcred(float* ws) {
    int out = blockIdx.x * 256 + threadIdx.x;   // 0..1023
    if (out >= 1024) return;
    int b = out >> 9, idx = out & 511;
    int kk = idx >> 5, v = idx & 31;
    const float* lamcp = ws + O_LAMCP;
    float S = 0.f;
    for (int c = 0; c < 216; ++c) S += lamcp[((long)b * 216 + c) * 512 + idx];
    float sv = ws[O_SARR + 64 + v], tv = ws[O_TARR + 64 + v];
    ws[O_LAMC + out] = sv * S * ws[O_RZI + b * 16 + kk] + tv;
}

// ---------------- fold q-BN into lam_c ----------------
__global__ __launch_bounds__(256) void klamc3(float* ws) {
    int tid = threadIdx.x;
    for (int i = tid; i < 4096; i += 256) {
        int b = i >> 11, r = i & 2047;
        int h = r >> 9, k = (r >> 5) & 15, v = r & 31;
        ws[O_LAMC2 + i] = ws[O_SARR + h * 16 + k] * ws[O_LAMC + b * 512 + k * 32 + v];
    }
    {
        int i = tid;
        int b = i >> 7, h = (i >> 5) & 3, v = i & 31;
        float s = 0.f;
#pragma unroll
        for (int k = 0; k < 16; ++k) s += ws[O_TARR + h * 16 + k] * ws[O_LAMC + b * 512 + k * 32 + v];
        ws[O_BC + i] = s;
    }
}

// ---------------- final fused: qw reassociation + bf16 swizzled vbn stencil + y_c ----------------
// vbn: [z=0..323][v=0..31] bf16; 16B slot s=v>>3 swizzled: s' = s ^ ((z ^ (z>>2)) & 3)
__global__ __launch_bounds__(256, 3) void kfinal(const float* __restrict__ qr, const float* __restrict__ vr,
                                                 const float* __restrict__ ws, float* __restrict__ y) {
    __shared__ unsigned int vbnu[324 * 16];   // 20736 B
    __shared__ float qw[27 * 256];            // 27648 B
    const float* sarr  = ws + O_SARR;
    const float* tarr  = ws + O_TARR;
    const float* swp   = ws + O_SW;
    const float* cwp   = ws + O_CW;
    const float* lamc2 = ws + O_LAMC2;
    const float* bcp   = ws + O_BC;

    int bid = blockIdx.x;                  // 0..3455
    int b = bid / 1728, t = bid - b * 1728;   // tiles: d 48 x h 12 x w 3
    int td = t / 36, r = t - td * 36;
    int th = r / 3, tw = r - th * 3;
    int d0 = td, h0 = th * 4, w0 = tw * 16;
    int tid = threadIdx.x;

    // phase A: halo load of BN'd v -> bf16 pair, swizzled [z][v] layout
    for (int i = tid; i < 16 * 324; i += 256) {
        int vp = i / 324, z = i - vp * 324;
        int zd = z / 108, rr = z - zd * 108;
        int zh = rr / 18, zw = rr - zh * 18;
        int gd = d0 - 1 + zd, gh = h0 - 1 + zh, gw = w0 - 1 + zw;
        float a = 0.f, c = 0.f;
        if ((unsigned)gd < 48u && (unsigned)gh < 48u && (unsigned)gw < 48u) {
            long gidx = ((long)b * 32 + 2 * vp) * NPOS + gd * 2304 + gh * 48 + gw;
            a = fmaf(vr[gidx], sarr[64 + 2 * vp], tarr[64 + 2 * vp]);
            c = fmaf(vr[gidx + NPOS], sarr[65 + 2 * vp], tarr[65 + 2 * vp]);
        }
        int sl = (vp >> 2) ^ ((z ^ (z >> 2)) & 3);
        vbnu[z * 16 + sl * 4 + (vp & 3)] = (unsigned int)f2bf(a) | ((unsigned int)f2bf(c) << 16);
    }

    // phase B: qw[o][h*64+pos]
    int pos = tid & 63;
    int wv = __builtin_amdgcn_readfirstlane(tid >> 6);
    int lh = pos >> 4, lw = pos & 15;
    int goff = d0 * 2304 + (h0 + lh) * 48 + (w0 + lw);
    {
        float qk[16];
        const float* qbase = qr + ((long)b * 64 + wv * 16) * NPOS + goff;
#pragma unroll
        for (int k = 0; k < 16; ++k) qk[k] = qbase[(long)k * NPOS];
#pragma unroll
        for (int o = 0; o < 27; ++o) {
            float a = cwp[wv * 27 + o];
            const float* swrow = swp + (wv * 27 + o) * 16;
#pragma unroll
            for (int k = 0; k < 16; ++k) a = fmaf(qk[k], swrow[k], a);
            qw[o * 256 + wv * 64 + pos] = a;
        }
    }
    __syncthreads();

    // phase C: (pos, v-group wv -> v0..v0+7)
    int v0 = wv * 8;
    float acc[4][8];
#pragma unroll
    for (int hh = 0; hh < 4; ++hh)
#pragma unroll
        for (int vi = 0; vi < 8; ++vi)
            acc[hh][vi] = bcp[(b * 4 + hh) * 32 + v0 + vi];

    // y_c: raw q * s_q-folded lam_c
    const float* qpb = qr + (long)b * 64 * NPOS + goff;
#pragma unroll
    for (int hh = 0; hh < 4; ++hh) {
#pragma unroll
        for (int k = 0; k < 16; ++k) {
            float qv = qpb[(long)(hh * 16 + k) * NPOS];
            const float* l2 = lamc2 + (((b * 4 + hh) * 16 + k) * 32) + v0;
#pragma unroll
            for (int vi = 0; vi < 8; ++vi) acc[hh][vi] = fmaf(qv, l2[vi], acc[hh][vi]);
        }
    }

    // y_p: 27-point stencil; one b128 yields all 8 v (bf16)
    int zb = lh * 18 + lw;
#pragma unroll
    for (int od = 0; od < 3; ++od)
#pragma unroll
    for (int oh = 0; oh < 3; ++oh)
#pragma unroll
    for (int ow = 0; ow < 3; ++ow) {
        int o = od * 9 + oh * 3 + ow;
        int z = zb + od * 108 + oh * 18 + ow;
        int sl = wv ^ ((z ^ (z >> 2)) & 3);
        uint4 u = *(const uint4*)(const void*)(vbnu + z * 16 + sl * 4);
        float sv[8];
        sv[0] = bflo(u.x); sv[1] = bfhi(u.x);
        sv[2] = bflo(u.y); sv[3] = bfhi(u.y);
        sv[4] = bflo(u.z); sv[5] = bfhi(u.z);
        sv[6] = bflo(u.w); sv[7] = bfhi(u.w);
        float q0 = qw[o * 256 + pos];
        float q1 = qw[o * 256 + 64 + pos];
        float q2 = qw[o * 256 + 128 + pos];
        float q3 = qw[o * 256 + 192 + pos];
#pragma unroll
        for (int vi = 0; vi < 8; ++vi) {
            acc[0][vi] = fmaf(q0, sv[vi], acc[0][vi]);
            acc[1][vi] = fmaf(q1, sv[vi], acc[1][vi]);
            acc[2][vi] = fmaf(q2, sv[vi], acc[2][vi]);
            acc[3][vi] = fmaf(q3, sv[vi], acc[3][vi]);
        }
    }

    long pbase = (long)b * 128 * NPOS + goff;
#pragma unroll
    for (int hh = 0; hh < 4; ++hh)
#pragma unroll
        for (int vi = 0; vi < 8; ++vi)
            y[pbase + (long)(hh * 32 + v0 + vi) * NPOS] = acc[hh][vi];
}

extern "C" void kernel_launch(void* const* d_in, const int* in_sizes, int n_in,
                              void* d_out, int out_size, void* d_ws, size_t ws_size,
                              hipStream_t stream) {
    const float* x    = (const float*)d_in[0];
    const float* Wq   = (const float*)d_in[1];
    const float* Wk   = (const float*)d_in[2];
    const float* Wv   = (const float*)d_in[3];
    const float* Wpos = (const float*)d_in[4];
    const float* gq   = (const float*)d_in[5];
    const float* bq   = (const float*)d_in[6];
    const float* gv   = (const float*)d_in[7];
    const float* bv   = (const float*)d_in[8];
    float* ws = (float*)d_ws;
    float* y  = (float*)d_out;
    float* qr = ws + O_Q;
    float* kr = ws + O_K;
    float* vr = ws + O_V;
    // partial-sum scratch inside d_out (fully overwritten by kfinal afterwards)
    float* PS = y;                 // [3456][112]
    float* PQ = y + 387072;        // [3456][112]
    float* PM = y + 774144;        // [3456][16]

    ksetup  <<<30,   256, 0, stream>>>(Wq, Wk, Wv, Wpos, ws);
    kproj   <<<3456, 256, 0, stream>>>(x, ws, qr, kr, vr, PS, PQ, PM);
    kred    <<<128,  256, 0, stream>>>(PS, PQ, PM, gq, bq, gv, bv, ws);
    klamcp  <<<432,  256, 0, stream>>>(kr, vr, ws, ws + O_LAMCP);
    kfin2   <<<1,    256, 0, stream>>>(ws);
    klamcred<<<4,    256, 0, stream>>>(ws);
    klamc3  <<<1,    256, 0, stream>>>(ws);
    kfinal  <<<3456, 256, 0, stream>>>(qr, vr, ws, y);
}

// Round 6
// 245.865 us; speedup vs baseline: 2.1233x; 1.1266x over previous
//
#include <hip/hip_runtime.h>
#include <math.h>

#define NPOS 110592   // 48*48*48
#define EPS 1e-5f

using bf16x8 = __attribute__((ext_vector_type(8))) short;
using f32x4  = __attribute__((ext_vector_type(4))) float;
using f32x2  = __attribute__((ext_vector_type(2))) float;

// ws layout (float-slot offsets)
constexpr long O_WB    = 0;        // 112x128 bf16 = 7168 slots (W[oc][c])
constexpr long O_WPT   = 7168;     // 27*16 fp32 (wposT[o][k])
constexpr long O_SARR  = 7600;     // 96  (BN scale: 0..63 q, 64..95 v)
constexpr long O_TARR  = 7696;     // 96  (BN shift)
constexpr long O_RMAX  = 7792;     // 32  (softmax rowmax per (b,k))
constexpr long O_ZP    = 7824;     // 432*16 softmax denom partials
constexpr long O_RZI   = 14736;    // 32 (1/Z)
constexpr long O_SW    = 14768;    // 4*27*16 (s_q-folded conv weights)
constexpr long O_CW    = 16496;    // 108(+pad) (t_q-folded conv bias)
constexpr long O_LAMC  = 16608;    // 2*16*32
constexpr long O_LAMC2 = 17632;    // 2*4*16*32 (s_q-folded lam_c)
constexpr long O_BC    = 21728;    // 2*4*32 (t_q-folded lam_c bias)
constexpr long O_LAMCP = 21984;    // 2*216*512 lam_c partials
constexpr long O_Q     = 243168;   // u32[2][32][NPOS] bf16-pairs = 7077888 slots
constexpr long O_K     = 7321056;  // f32[2][16][NPOS] = 3538944
constexpr long O_V     = 10860000; // u32[2][16][NPOS] bf16-pairs = 3538944
// total 14398944 slots = 57.6 MB

__device__ inline unsigned short f2bf(float f) {
    unsigned int u = __float_as_uint(f);
    u += 0x7FFFu + ((u >> 16) & 1u);   // RNE
    return (unsigned short)(u >> 16);
}
__device__ inline float bflo(unsigned int u) { return __uint_as_float(u << 16); }
__device__ inline float bfhi(unsigned int u) { return __uint_as_float(u & 0xFFFF0000u); }
__device__ inline unsigned int cvtpk(float a, float b) {
    unsigned int r;
    asm("v_cvt_pk_bf16_f32 %0, %1, %2" : "=v"(r) : "v"(a), "v"(b));
    return r;
}
__device__ inline void pkfma(f32x2& c, f32x2 a, f32x2 b) {
    asm("v_pk_fma_f32 %0, %1, %2, %0" : "+v"(c) : "v"(a), "v"(b));
}

// ---------------- setup: bf16 weights [oc][c] + wposT ----------------
__global__ __launch_bounds__(256) void ksetup(const float* Wq, const float* Wk, const float* Wv,
                                              const float* Wpos, float* ws) {
    int i = blockIdx.x * 256 + threadIdx.x;
    if (i < 7168) {
        int oc = i >> 6, cp = i & 63;
        int c = 2 * cp;
        float v0, v1;
        if (oc < 64)      { v0 = Wq[oc * 128 + c];        v1 = Wq[oc * 128 + c + 1]; }
        else if (oc < 80) { v0 = Wk[(oc - 64) * 128 + c]; v1 = Wk[(oc - 64) * 128 + c + 1]; }
        else              { v0 = Wv[(oc - 80) * 128 + c]; v1 = Wv[(oc - 80) * 128 + c + 1]; }
        ((unsigned int*)(ws + O_WB))[i] = (unsigned int)f2bf(v0) | ((unsigned int)f2bf(v1) << 16);
    } else if (i < 7600) {
        int j = i - 7168;
        int o = j >> 4, k = j & 15;
        ws[O_WPT + j] = Wpos[k * 27 + o];   // o = od*9+oh*3+ow
    }
}

// ---------------- projection via MFMA + fused stat partials ----------------
__global__ __launch_bounds__(256, 4) void kproj(const float* __restrict__ x, const float* __restrict__ ws,
                                                unsigned int* __restrict__ qu, float* __restrict__ kr,
                                                unsigned int* __restrict__ vu,
                                                float* __restrict__ PS, float* __restrict__ PQ,
                                                float* __restrict__ PM) {
    __shared__ unsigned int xsu[64 * 68];   // [pos][c] bf16
    __shared__ float pss[4 * 112], psq[4 * 112], pmx[4 * 16];
    const unsigned short* WBu = (const unsigned short*)(ws + O_WB);

    int blk = blockIdx.x;                 // 0..3455
    int b = blk / 1728, tile = blk - b * 1728;
    long base = (long)b * 128 * NPOS + (long)tile * 64;
    int tid = threadIdx.x;

    for (int i = tid; i < 64 * 64; i += 256) {
        int cp = i >> 6, p = i & 63;
        float v0 = x[base + (long)(2 * cp) * NPOS + p];
        float v1 = x[base + (long)(2 * cp + 1) * NPOS + p];
        xsu[p * 68 + cp] = cvtpk(v0, v1);
    }
    __syncthreads();

    int lane = tid & 63;
    int wv = __builtin_amdgcn_readfirstlane(tid >> 6);
    int r = lane & 15, g = lane >> 4;

    f32x4 acc[7];
#pragma unroll
    for (int t = 0; t < 7; ++t) acc[t] = (f32x4){0.f, 0.f, 0.f, 0.f};

    const unsigned short* xrow = (const unsigned short*)xsu + (wv * 16 + r) * 136;
#pragma unroll
    for (int ks = 0; ks < 4; ++ks) {
        bf16x8 bfrag = *(const bf16x8*)(const void*)(xrow + ks * 32 + g * 8);
#pragma unroll
        for (int t = 0; t < 7; ++t) {
            bf16x8 afrag = *(const bf16x8*)(const void*)(WBu + (t * 16 + r) * 128 + ks * 32 + g * 8);
            acc[t] = __builtin_amdgcn_mfma_f32_16x16x32_bf16(afrag, bfrag, acc[t], 0, 0, 0);
        }
    }

    long pos = (long)tile * 64 + wv * 16 + r;
    // q (t 0..3): bf16-pair u32
#pragma unroll
    for (int t = 0; t < 4; ++t)
#pragma unroll
        for (int jp = 0; jp < 2; ++jp)
            qu[((long)b * 32 + t * 8 + g * 2 + jp) * NPOS + pos] = cvtpk(acc[t][2 * jp], acc[t][2 * jp + 1]);
    // k (t=4): fp32
#pragma unroll
    for (int j = 0; j < 4; ++j)
        kr[((long)b * 16 + g * 4 + j) * NPOS + pos] = acc[4][j];
    // v (t 5..6): bf16-pair u32
#pragma unroll
    for (int t = 5; t < 7; ++t)
#pragma unroll
        for (int jp = 0; jp < 2; ++jp)
            vu[((long)b * 16 + (t - 5) * 8 + g * 2 + jp) * NPOS + pos] = cvtpk(acc[t][2 * jp], acc[t][2 * jp + 1]);

    // fused stat partials (on fp32 pre-rounding values)
#pragma unroll
    for (int t = 0; t < 7; ++t) {
#pragma unroll
        for (int j = 0; j < 4; ++j) {
            float s = acc[t][j];
            float q = s * s;
#pragma unroll
            for (int m = 1; m < 16; m <<= 1) {
                s += __shfl_xor(s, m, 64);
                q += __shfl_xor(q, m, 64);
            }
            if (r == 0) {
                int oc = t * 16 + g * 4 + j;
                pss[wv * 112 + oc] = s;
                psq[wv * 112 + oc] = q;
            }
        }
    }
#pragma unroll
    for (int j = 0; j < 4; ++j) {
        float m = acc[4][j];
#pragma unroll
        for (int mm = 1; mm < 16; mm <<= 1) m = fmaxf(m, __shfl_xor(m, mm, 64));
        if (r == 0) pmx[wv * 16 + g * 4 + j] = m;
    }
    __syncthreads();
    if (tid < 112) {
        float s = pss[tid] + pss[112 + tid] + pss[224 + tid] + pss[336 + tid];
        float q = psq[tid] + psq[112 + tid] + psq[224 + tid] + psq[336 + tid];
        PS[(long)blk * 112 + tid] = s;
        PQ[(long)blk * 112 + tid] = q;
    } else if (tid < 128) {
        int kk = tid - 112;
        PM[(long)blk * 16 + kk] = fmaxf(fmaxf(pmx[kk], pmx[16 + kk]),
                                        fmaxf(pmx[32 + kk], pmx[48 + kk]));
    }
}

// ---------------- reduce partials: BN scale/shift + k rowmax ----------------
__global__ __launch_bounds__(256) void kred(const float* __restrict__ PS, const float* __restrict__ PQ,
                                            const float* __restrict__ PM,
                                            const float* gq, const float* bq,
                                            const float* gv, const float* bv, float* ws) {
    __shared__ float rs[256], rq[256];
    int bid = blockIdx.x, tid = threadIdx.x;
    if (bid < 96) {
        int c = bid;
        int oc = c < 64 ? c : c + 16;
        float s = 0.f, q = 0.f;
        for (int i = tid; i < 3456; i += 256) {
            s += PS[(long)i * 112 + oc];
            q += PQ[(long)i * 112 + oc];
        }
        rs[tid] = s; rq[tid] = q;
        __syncthreads();
        for (int st = 128; st > 0; st >>= 1) {
            if (tid < st) { rs[tid] += rs[tid + st]; rq[tid] += rq[tid + st]; }
            __syncthreads();
        }
        if (tid == 0) {
            const float inv_n = 1.f / 221184.f;
            float mean = rs[0] * inv_n;
            float var = rq[0] * inv_n - mean * mean;
            float g = c < 64 ? gq[c] : gv[c - 64];
            float bb = c < 64 ? bq[c] : bv[c - 64];
            float sc = g * rsqrtf(var + EPS);
            ws[O_SARR + c] = sc;
            ws[O_TARR + c] = bb - mean * sc;
        }
    } else {
        int row = bid - 96;
        int b = row >> 4, kk = row & 15;
        float m = -1e30f;
        for (int i = tid; i < 1728; i += 256) m = fmaxf(m, PM[((long)b * 1728 + i) * 16 + kk]);
        rs[tid] = m;
        __syncthreads();
        for (int st = 128; st > 0; st >>= 1) {
            if (tid < st) rs[tid] = fmaxf(rs[tid], rs[tid + st]);
            __syncthreads();
        }
        if (tid == 0) ws[O_RMAX + row] = rs[0];
    }
}

// ---------------- lam_c partials + softmax Z partials ----------------
__global__ __launch_bounds__(256) void klamcp(const float* __restrict__ kr, const unsigned int* __restrict__ vu,
                                              float* __restrict__ ws, float* __restrict__ lamcp) {
    __shared__ float es[16 * 512];
    const float* rmax = ws + O_RMAX;
    int bid = blockIdx.x;                  // 0..431
    int b = bid / 216, chunk = bid - b * 216;
    long p0 = (long)chunk * 512;
    int tid = threadIdx.x;
    for (int i = tid; i < 16 * 512; i += 256) {
        int rr = i >> 9, p = i & 511;
        es[i] = expf(kr[((long)b * 16 + rr) * NPOS + p0 + p] - rmax[b * 16 + rr]);
    }
    __syncthreads();
    int vp = tid >> 4, pl = tid & 15;
    const unsigned int* vpp = vu + ((long)b * 16 + vp) * NPOS + p0;
    float acc0[16], acc1[16];
#pragma unroll
    for (int k = 0; k < 16; ++k) { acc0[k] = 0.f; acc1[k] = 0.f; }
    for (int j = 0; j < 32; ++j) {
        int p = pl + 16 * j;
        unsigned int u = vpp[p];
        float v0 = bflo(u), v1 = bfhi(u);
#pragma unroll
        for (int k = 0; k < 16; ++k) {
            float e = es[k * 512 + p];
            acc0[k] = fmaf(e, v0, acc0[k]);
            acc1[k] = fmaf(e, v1, acc1[k]);
        }
    }
#pragma unroll
    for (int m = 1; m < 16; m <<= 1) {
#pragma unroll
        for (int k = 0; k < 16; ++k) {
            acc0[k] += __shfl_xor(acc0[k], m, 64);
            acc1[k] += __shfl_xor(acc1[k], m, 64);
        }
    }
    if (pl == 0) {
        long base = (long)bid * 512;
#pragma unroll
        for (int k = 0; k < 16; ++k) {
            lamcp[base + k * 32 + 2 * vp]     = acc0[k];
            lamcp[base + k * 32 + 2 * vp + 1] = acc1[k];
        }
    }
    {
        int rr = tid >> 4, j = tid & 15;
        float s = 0.f;
        const float* er = es + rr * 512 + j * 32;
#pragma unroll 8
        for (int i = 0; i < 32; ++i) s += er[i];
#pragma unroll
        for (int m = 1; m < 16; m <<= 1) s += __shfl_xor(s, m, 64);
        if (j == 0) ws[O_ZP + (long)bid * 16 + rr] = s;
    }
}

// ---------------- finalize Z, fold BN into conv weights ----------------
__global__ __launch_bounds__(256) void kfin2(float* ws) {
    int tid = threadIdx.x;
    if (tid < 32) {
        int b = tid >> 4, kk = tid & 15;
        float s = 0.f;
        for (int c = 0; c < 216; ++c) s += ws[O_ZP + ((long)b * 216 + c) * 16 + kk];
        ws[O_RZI + tid] = 1.f / s;
    }
    for (int i = tid; i < 1728; i += 256) {
        int h = i / 432, r = i - h * 432, o = r >> 4, k = r & 15;
        ws[O_SW + i] = ws[O_SARR + h * 16 + k] * ws[O_WPT + o * 16 + k];
    }
    if (tid < 108) {
        int h = tid / 27, o = tid - h * 27;
        float s = 0.f;
        for (int k = 0; k < 16; ++k) s += ws[O_TARR + h * 16 + k] * ws[O_WPT + o * 16 + k];
        ws[O_CW + tid] = s;
    }
}

// ---------------- reduce lam_c partials + fold BN + 1/Z ----------------
__global__ __launch_bounds__(256) void klamcred(float* ws) {
    int out = blockIdx.x * 256 + threadIdx.x;
    if (out >= 1024) return;
    int b = out >> 9, idx = out & 511;
    int kk = idx >> 5, v = idx & 31;
    const float* lamcp = ws + O_LAMCP;
    float S = 0.f;
    for (int c = 0; c < 216; ++c) S += lamcp[((long)b * 216 + c) * 512 + idx];
    float sv = ws[O_SARR + 64 + v], tv = ws[O_TARR + 64 + v];
    ws[O_LAMC + out] = sv * S * ws[O_RZI + b * 16 + kk] + tv;
}

// ---------------- fold q-BN into lam_c ----------------
__global__ __launch_bounds__(256) void klamc3(float* ws) {
    int tid = threadIdx.x;
    for (int i = tid; i < 4096; i += 256) {
        int b = i >> 11, r = i & 2047;
        int h = r >> 9, k = (r >> 5) & 15, v = r & 31;
        ws[O_LAMC2 + i] = ws[O_SARR + h * 16 + k] * ws[O_LAMC + b * 512 + k * 32 + v];
    }
    {
        int i = tid;
        int b = i >> 7, h = (i >> 5) & 3, v = i & 31;
        float s = 0.f;
#pragma unroll
        for (int k = 0; k < 16; ++k) s += ws[O_TARR + h * 16 + k] * ws[O_LAMC + b * 512 + k * 32 + v];
        ws[O_BC + i] = s;
    }
}

// ---------------- final fused kernel ----------------
// tile (d,h,w) = (2,4,16) = 128 pos, 512 threads (8 waves), halo z = 0..431
// wave wv: hsel=wv&3 (phase B h), vg=wv&3 (phase C v-group), psel=wv>>2 (d-half)
__global__ __launch_bounds__(512, 4) void kfinal(const unsigned int* __restrict__ qu,
                                                 const unsigned int* __restrict__ vu,
                                                 const float* __restrict__ ws, float* __restrict__ y) {
    __shared__ unsigned int vbnu[432 * 16];      // 27648 B: [z][8 slots x 16B], swz sl^=((z^(z>>2))&3)
    __shared__ unsigned short qwh[27 * 128 * 4]; // 27648 B: [o][pos][h] bf16
    __shared__ unsigned int qsu[128 * 32];       // 16384 B: [pos][8 slots x 16B], swz sl^=(pos&7)
    const float* sarr  = ws + O_SARR;
    const float* tarr  = ws + O_TARR;
    const float* swp   = ws + O_SW;
    const float* cwp   = ws + O_CW;
    const float* lamc2 = ws + O_LAMC2;
    const float* bcp   = ws + O_BC;

    int bid = blockIdx.x;                     // 0..1727
    int b = bid / 864, t = bid - b * 864;     // tiles: d 24 x h 12 x w 3
    int td = t / 36, r = t - td * 36;
    int th = r / 3, tw = r - th * 3;
    int d0 = td * 2, h0 = th * 4, w0 = tw * 16;
    int tid = threadIdx.x;

    // phase A: halo load of packed v -> BN -> bf16 pair, swizzled [z][v]
    for (int i = tid; i < 16 * 432; i += 512) {
        int vp = i / 432, z = i - vp * 432;
        int zd = z / 108, rr = z - zd * 108;
        int zh = rr / 18, zw = rr - zh * 18;
        int gd = d0 - 1 + zd, gh = h0 - 1 + zh, gw = w0 - 1 + zw;
        unsigned int out = 0u;
        if ((unsigned)gd < 48u && (unsigned)gh < 48u && (unsigned)gw < 48u) {
            unsigned int u = vu[((long)b * 16 + vp) * NPOS + gd * 2304 + gh * 48 + gw];
            float a = fmaf(bflo(u), sarr[64 + 2 * vp], tarr[64 + 2 * vp]);
            float c = fmaf(bfhi(u), sarr[65 + 2 * vp], tarr[65 + 2 * vp]);
            out = cvtpk(a, c);
        }
        int sl = (vp >> 2) ^ ((z ^ (z >> 2)) & 3);
        vbnu[z * 16 + sl * 4 + (vp & 3)] = out;
    }

    // phase B: qw + q stash
    int lane = tid & 63;
    int wv = __builtin_amdgcn_readfirstlane(tid >> 6);
    int hsel = wv & 3, psel = wv >> 2;
    int pos_l = psel * 64 + lane;
    int lh = lane >> 4, lw = lane & 15;
    int goff = (d0 + psel) * 2304 + (h0 + lh) * 48 + (w0 + lw);
    {
        unsigned int uq[8];
        float qk[16];
        const unsigned int* qb = qu + ((long)b * 32 + hsel * 8) * NPOS + goff;
#pragma unroll
        for (int m = 0; m < 8; ++m) {
            uq[m] = qb[(long)m * NPOS];
            qk[2 * m] = bflo(uq[m]);
            qk[2 * m + 1] = bfhi(uq[m]);
        }
#pragma unroll
        for (int o = 0; o < 27; ++o) {
            float a = cwp[hsel * 27 + o];
            const float* swrow = swp + (hsel * 27 + o) * 16;
#pragma unroll
            for (int k = 0; k < 16; ++k) a = fmaf(qk[k], swrow[k], a);
            qwh[(o * 128 + pos_l) * 4 + hsel] = (unsigned short)cvtpk(a, a);
        }
        // stash packed q (already bf16 pairs) into swizzled qsu
        uint4 w0v = make_uint4(uq[0], uq[1], uq[2], uq[3]);
        uint4 w1v = make_uint4(uq[4], uq[5], uq[6], uq[7]);
        *(uint4*)(qsu + pos_l * 32 + (((2 * hsel) ^ (pos_l & 7)) << 2)) = w0v;
        *(uint4*)(qsu + pos_l * 32 + (((2 * hsel + 1) ^ (pos_l & 7)) << 2)) = w1v;
    }
    __syncthreads();

    // phase C: (pos_l, v-group vg -> v0..v0+7), all 4 h
    int vg = wv & 3;
    int v0 = vg * 8;
    f32x2 acc2[4][4];
#pragma unroll
    for (int hh = 0; hh < 4; ++hh)
#pragma unroll
        for (int p = 0; p < 4; ++p) {
            acc2[hh][p][0] = bcp[(b * 4 + hh) * 32 + v0 + 2 * p];
            acc2[hh][p][1] = bcp[(b * 4 + hh) * 32 + v0 + 2 * p + 1];
        }

    // y_c: q (bf16 from LDS) x s_q-folded lam_c (uniform -> SGPR)
#pragma unroll
    for (int s = 0; s < 8; ++s) {
        uint4 uq = *(const uint4*)(qsu + pos_l * 32 + ((s ^ (pos_l & 7)) << 2));
        int hh = s >> 1, k0 = (s & 1) * 8;
        float qa[8];
        qa[0] = bflo(uq.x); qa[1] = bfhi(uq.x);
        qa[2] = bflo(uq.y); qa[3] = bfhi(uq.y);
        qa[4] = bflo(uq.z); qa[5] = bfhi(uq.z);
        qa[6] = bflo(uq.w); qa[7] = bfhi(uq.w);
#pragma unroll
        for (int j = 0; j < 8; ++j) {
            const float* l2 = lamc2 + (((b * 4 + hh) * 16 + k0 + j) << 5) + v0;
#pragma unroll
            for (int p = 0; p < 4; ++p) {
                acc2[hh][p][0] = fmaf(qa[j], l2[2 * p], acc2[hh][p][0]);
                acc2[hh][p][1] = fmaf(qa[j], l2[2 * p + 1], acc2[hh][p][1]);
            }
        }
    }

    // y_p: 27-point stencil with packed-fp32 FMA
    int zb = psel * 108 + lh * 18 + lw;
#pragma unroll
    for (int od = 0; od < 3; ++od)
#pragma unroll
    for (int oh = 0; oh < 3; ++oh)
#pragma unroll
    for (int ow = 0; ow < 3; ++ow) {
        int o = od * 9 + oh * 3 + ow;
        int z = zb + od * 108 + oh * 18 + ow;
        int sl = vg ^ ((z ^ (z >> 2)) & 3);
        uint4 u = *(const uint4*)(vbnu + z * 16 + (sl << 2));
        uint2 uqw = *(const uint2*)(qwh + ((o * 128 + pos_l) << 2));
        f32x2 s0; s0[0] = bflo(u.x); s0[1] = bfhi(u.x);
        f32x2 s1; s1[0] = bflo(u.y); s1[1] = bfhi(u.y);
        f32x2 s2; s2[0] = bflo(u.z); s2[1] = bfhi(u.z);
        f32x2 s3; s3[0] = bflo(u.w); s3[1] = bfhi(u.w);
        float q0 = bflo(uqw.x), q1 = bfhi(uqw.x);
        float q2 = bflo(uqw.y), q3 = bfhi(uqw.y);
        f32x2 qd0; qd0[0] = q0; qd0[1] = q0;
        f32x2 qd1; qd1[0] = q1; qd1[1] = q1;
        f32x2 qd2; qd2[0] = q2; qd2[1] = q2;
        f32x2 qd3; qd3[0] = q3; qd3[1] = q3;
        pkfma(acc2[0][0], qd0, s0); pkfma(acc2[0][1], qd0, s1);
        pkfma(acc2[0][2], qd0, s2); pkfma(acc2[0][3], qd0, s3);
        pkfma(acc2[1][0], qd1, s0); pkfma(acc2[1][1], qd1, s1);
        pkfma(acc2[1][2], qd1, s2); pkfma(acc2[1][3], qd1, s3);
        pkfma(acc2[2][0], qd2, s0); pkfma(acc2[2][1], qd2, s1);
        pkfma(acc2[2][2], qd2, s2); pkfma(acc2[2][3], qd2, s3);
        pkfma(acc2[3][0], qd3, s0); pkfma(acc2[3][1], qd3, s1);
        pkfma(acc2[3][2], qd3, s2); pkfma(acc2[3][3], qd3, s3);
    }

    long pbase = (long)b * 128 * NPOS + goff;
#pragma unroll
    for (int hh = 0; hh < 4; ++hh)
#pragma unroll
        for (int p = 0; p < 4; ++p) {
            y[pbase + (long)(hh * 32 + v0 + 2 * p) * NPOS]     = acc2[hh][p][0];
            y[pbase + (long)(hh * 32 + v0 + 2 * p + 1) * NPOS] = acc2[hh][p][1];
        }
}

extern "C" void kernel_launch(void* const* d_in, const int* in_sizes, int n_in,
                              void* d_out, int out_size, void* d_ws, size_t ws_size,
                              hipStream_t stream) {
    const float* x    = (const float*)d_in[0];
    const float* Wq   = (const float*)d_in[1];
    const float* Wk   = (const float*)d_in[2];
    const float* Wv   = (const float*)d_in[3];
    const float* Wpos = (const float*)d_in[4];
    const float* gq   = (const float*)d_in[5];
    const float* bq   = (const float*)d_in[6];
    const float* gv   = (const float*)d_in[7];
    const float* bv   = (const float*)d_in[8];
    float* ws = (float*)d_ws;
    float* y  = (float*)d_out;
    unsigned int* qu = (unsigned int*)(ws + O_Q);
    float*        kr = ws + O_K;
    unsigned int* vu = (unsigned int*)(ws + O_V);
    // partial-sum scratch inside d_out (fully overwritten by kfinal afterwards)
    float* PS = y;                 // [3456][112]
    float* PQ = y + 387072;        // [3456][112]
    float* PM = y + 774144;        // [3456][16]

    ksetup  <<<30,   256, 0, stream>>>(Wq, Wk, Wv, Wpos, ws);
    kproj   <<<3456, 256, 0, stream>>>(x, ws, qu, kr, vu, PS, PQ, PM);
    kred    <<<128,  256, 0, stream>>>(PS, PQ, PM, gq, bq, gv, bv, ws);
    klamcp  <<<432,  256, 0, stream>>>(kr, vu, ws, ws + O_LAMCP);
    kfin2   <<<1,    256, 0, stream>>>(ws);
    klamcred<<<4,    256, 0, stream>>>(ws);
    klamc3  <<<1,    256, 0, stream>>>(ws);
    kfinal  <<<1728, 512, 0, stream>>>(qu, vu, ws, y);
}

// Round 10
// 239.851 us; speedup vs baseline: 2.1765x; 1.0251x over previous
//
#include <hip/hip_runtime.h>
#include <math.h>

#define NPOS 110592   // 48*48*48
#define EPS 1e-5f

using bf16x8 = __attribute__((ext_vector_type(8))) short;
using f32x4  = __attribute__((ext_vector_type(4))) float;
using f32x2  = __attribute__((ext_vector_type(2))) float;

// ws layout (float-slot offsets)
constexpr long O_WB    = 0;        // 112x128 bf16 = 7168 slots (W[oc][c])
constexpr long O_WPT   = 7168;     // 27*16 fp32 (wposT[o][k])
constexpr long O_SARR  = 7600;     // 96  (BN scale: 0..63 q, 64..95 v)
constexpr long O_TARR  = 7696;     // 96  (BN shift)
constexpr long O_RMAX  = 7792;     // 32  (softmax rowmax per (b,k))
constexpr long O_ZP    = 7824;     // 432*16 softmax denom partials
constexpr long O_RZI   = 14736;    // 32 (1/Z)
constexpr long O_SW    = 14768;    // 4*27*16 (s_q-folded conv weights)
constexpr long O_CW    = 16496;    // 108(+pad) (t_q-folded conv bias)
constexpr long O_LAMC  = 16608;    // 2*16*32
constexpr long O_LAMC2 = 17632;    // 2*4*16*32 (s_q-folded lam_c)
constexpr long O_BC    = 21728;    // 2*4*32 (t_q-folded lam_c bias)
constexpr long O_LAMCP = 21984;    // 2*216*512 lam_c partials
constexpr long O_Q     = 243168;   // u32[2][32][NPOS] bf16-pairs
constexpr long O_K     = 7321056;  // f32[2][16][NPOS]
constexpr long O_V     = 10860000; // u32[2][16][NPOS] bf16-pairs
// total ~57.6 MB

__device__ inline unsigned short f2bf(float f) {
    unsigned int u = __float_as_uint(f);
    u += 0x7FFFu + ((u >> 16) & 1u);   // RNE
    return (unsigned short)(u >> 16);
}
__device__ inline float bflo(unsigned int u) { return __uint_as_float(u << 16); }
__device__ inline float bfhi(unsigned int u) { return __uint_as_float(u & 0xFFFF0000u); }
__device__ inline unsigned int cvtpk(float a, float b) {
    unsigned int r;
    asm("v_cvt_pk_bf16_f32 %0, %1, %2" : "=v"(r) : "v"(a), "v"(b));
    return r;
}
__device__ inline void pkfma(f32x2& c, f32x2 a, f32x2 b) {
    asm("v_pk_fma_f32 %0, %1, %2, %0" : "+v"(c) : "v"(a), "v"(b));
}

// ---------------- setup: bf16 weights [oc][c] + wposT ----------------
__global__ __launch_bounds__(256) void ksetup(const float* Wq, const float* Wk, const float* Wv,
                                              const float* Wpos, float* ws) {
    int i = blockIdx.x * 256 + threadIdx.x;
    if (i < 7168) {
        int oc = i >> 6, cp = i & 63;
        int c = 2 * cp;
        float v0, v1;
        if (oc < 64)      { v0 = Wq[oc * 128 + c];        v1 = Wq[oc * 128 + c + 1]; }
        else if (oc < 80) { v0 = Wk[(oc - 64) * 128 + c]; v1 = Wk[(oc - 64) * 128 + c + 1]; }
        else              { v0 = Wv[(oc - 80) * 128 + c]; v1 = Wv[(oc - 80) * 128 + c + 1]; }
        ((unsigned int*)(ws + O_WB))[i] = (unsigned int)f2bf(v0) | ((unsigned int)f2bf(v1) << 16);
    } else if (i < 7600) {
        int j = i - 7168;
        int o = j >> 4, k = j & 15;
        ws[O_WPT + j] = Wpos[k * 27 + o];   // o = od*9+oh*3+ow
    }
}

// ---------------- projection via MFMA + fused stat partials ----------------
__global__ __launch_bounds__(256, 4) void kproj(const float* __restrict__ x, const float* __restrict__ ws,
                                                unsigned int* __restrict__ qu, float* __restrict__ kr,
                                                unsigned int* __restrict__ vu,
                                                float* __restrict__ PS, float* __restrict__ PQ,
                                                float* __restrict__ PM) {
    __shared__ unsigned int xsu[64 * 68];   // [pos][c] bf16
    __shared__ float pss[4 * 112], psq[4 * 112], pmx[4 * 16];
    const unsigned short* WBu = (const unsigned short*)(ws + O_WB);

    int blk0 = blockIdx.x;                // XCD-aware bijective swizzle (grid 3456 = 8*432)
    int blk = (blk0 & 7) * 432 + (blk0 >> 3);
    int b = blk / 1728, tile = blk - b * 1728;
    long base = (long)b * 128 * NPOS + (long)tile * 64;
    int tid = threadIdx.x;

    for (int i = tid; i < 64 * 64; i += 256) {
        int cp = i >> 6, p = i & 63;
        float v0 = x[base + (long)(2 * cp) * NPOS + p];
        float v1 = x[base + (long)(2 * cp + 1) * NPOS + p];
        xsu[p * 68 + cp] = cvtpk(v0, v1);
    }
    __syncthreads();

    int lane = tid & 63;
    int wv = __builtin_amdgcn_readfirstlane(tid >> 6);
    int r = lane & 15, g = lane >> 4;

    f32x4 acc[7];
#pragma unroll
    for (int t = 0; t < 7; ++t) acc[t] = (f32x4){0.f, 0.f, 0.f, 0.f};

    const unsigned short* xrow = (const unsigned short*)xsu + (wv * 16 + r) * 136;
#pragma unroll
    for (int ks = 0; ks < 4; ++ks) {
        bf16x8 bfrag = *(const bf16x8*)(const void*)(xrow + ks * 32 + g * 8);
#pragma unroll
        for (int t = 0; t < 7; ++t) {
            bf16x8 afrag = *(const bf16x8*)(const void*)(WBu + (t * 16 + r) * 128 + ks * 32 + g * 8);
            acc[t] = __builtin_amdgcn_mfma_f32_16x16x32_bf16(afrag, bfrag, acc[t], 0, 0, 0);
        }
    }

    long pos = (long)tile * 64 + wv * 16 + r;
    // q (t 0..3): bf16-pair u32
#pragma unroll
    for (int t = 0; t < 4; ++t)
#pragma unroll
        for (int jp = 0; jp < 2; ++jp)
            qu[((long)b * 32 + t * 8 + g * 2 + jp) * NPOS + pos] = cvtpk(acc[t][2 * jp], acc[t][2 * jp + 1]);
    // k (t=4): fp32
#pragma unroll
    for (int j = 0; j < 4; ++j)
        kr[((long)b * 16 + g * 4 + j) * NPOS + pos] = acc[4][j];
    // v (t 5..6): bf16-pair u32
#pragma unroll
    for (int t = 5; t < 7; ++t)
#pragma unroll
        for (int jp = 0; jp < 2; ++jp)
            vu[((long)b * 16 + (t - 5) * 8 + g * 2 + jp) * NPOS + pos] = cvtpk(acc[t][2 * jp], acc[t][2 * jp + 1]);

    // fused stat partials (on fp32 pre-rounding values)
#pragma unroll
    for (int t = 0; t < 7; ++t) {
#pragma unroll
        for (int j = 0; j < 4; ++j) {
            float s = acc[t][j];
            float q = s * s;
#pragma unroll
            for (int m = 1; m < 16; m <<= 1) {
                s += __shfl_xor(s, m, 64);
                q += __shfl_xor(q, m, 64);
            }
            if (r == 0) {
                int oc = t * 16 + g * 4 + j;
                pss[wv * 112 + oc] = s;
                psq[wv * 112 + oc] = q;
            }
        }
    }
#pragma unroll
    for (int j = 0; j < 4; ++j) {
        float m = acc[4][j];
#pragma unroll
        for (int mm = 1; mm < 16; mm <<= 1) m = fmaxf(m, __shfl_xor(m, mm, 64));
        if (r == 0) pmx[wv * 16 + g * 4 + j] = m;
    }
    __syncthreads();
    if (tid < 112) {
        float s = pss[tid] + pss[112 + tid] + pss[224 + tid] + pss[336 + tid];
        float q = psq[tid] + psq[112 + tid] + psq[224 + tid] + psq[336 + tid];
        PS[(long)blk * 112 + tid] = s;
        PQ[(long)blk * 112 + tid] = q;
    } else if (tid < 128) {
        int kk = tid - 112;
        PM[(long)blk * 16 + kk] = fmaxf(fmaxf(pmx[kk], pmx[16 + kk]),
                                        fmaxf(pmx[32 + kk], pmx[48 + kk]));
    }
}

// ---------------- reduce partials: BN scale/shift + k rowmax ----------------
__global__ __launch_bounds__(256) void kred(const float* __restrict__ PS, const float* __restrict__ PQ,
                                            const float* __restrict__ PM,
                                            const float* gq, const float* bq,
                                            const float* gv, const float* bv, float* ws) {
    __shared__ float rs[256], rq[256];
    int bid = blockIdx.x, tid = threadIdx.x;
    if (bid < 96) {
        int c = bid;
        int oc = c < 64 ? c : c + 16;
        float s = 0.f, q = 0.f;
        for (int i = tid; i < 3456; i += 256) {
            s += PS[(long)i * 112 + oc];
            q += PQ[(long)i * 112 + oc];
        }
        rs[tid] = s; rq[tid] = q;
        __syncthreads();
        for (int st = 128; st > 0; st >>= 1) {
            if (tid < st) { rs[tid] += rs[tid + st]; rq[tid] += rq[tid + st]; }
            __syncthreads();
        }
        if (tid == 0) {
            const float inv_n = 1.f / 221184.f;
            float mean = rs[0] * inv_n;
            float var = rq[0] * inv_n - mean * mean;
            float g = c < 64 ? gq[c] : gv[c - 64];
            float bb = c < 64 ? bq[c] : bv[c - 64];
            float sc = g * rsqrtf(var + EPS);
            ws[O_SARR + c] = sc;
            ws[O_TARR + c] = bb - mean * sc;
        }
    } else {
        int row = bid - 96;
        int b = row >> 4, kk = row & 15;
        float m = -1e30f;
        for (int i = tid; i < 1728; i += 256) m = fmaxf(m, PM[((long)b * 1728 + i) * 16 + kk]);
        rs[tid] = m;
        __syncthreads();
        for (int st = 128; st > 0; st >>= 1) {
            if (tid < st) rs[tid] = fmaxf(rs[tid], rs[tid + st]);
            __syncthreads();
        }
        if (tid == 0) ws[O_RMAX + row] = rs[0];
    }
}

// ---------------- lam_c partials + softmax Z partials ----------------
__global__ __launch_bounds__(256) void klamcp(const float* __restrict__ kr, const unsigned int* __restrict__ vu,
                                              float* __restrict__ ws, float* __restrict__ lamcp) {
    __shared__ float es[16 * 512];
    const float* rmax = ws + O_RMAX;
    int bid = blockIdx.x;                  // 0..431
    int b = bid / 216, chunk = bid - b * 216;
    long p0 = (long)chunk * 512;
    int tid = threadIdx.x;
    for (int i = tid; i < 16 * 512; i += 256) {
        int rr = i >> 9, p = i & 511;
        es[i] = expf(kr[((long)b * 16 + rr) * NPOS + p0 + p] - rmax[b * 16 + rr]);
    }
    __syncthreads();
    int vp = tid >> 4, pl = tid & 15;
    const unsigned int* vpp = vu + ((long)b * 16 + vp) * NPOS + p0;
    float acc0[16], acc1[16];
#pragma unroll
    for (int k = 0; k < 16; ++k) { acc0[k] = 0.f; acc1[k] = 0.f; }
    for (int j = 0; j < 32; ++j) {
        int p = pl + 16 * j;
        unsigned int u = vpp[p];
        float v0 = bflo(u), v1 = bfhi(u);
#pragma unroll
        for (int k = 0; k < 16; ++k) {
            float e = es[k * 512 + p];
            acc0[k] = fmaf(e, v0, acc0[k]);
            acc1[k] = fmaf(e, v1, acc1[k]);
        }
    }
#pragma unroll
    for (int m = 1; m < 16; m <<= 1) {
#pragma unroll
        for (int k = 0; k < 16; ++k) {
            acc0[k] += __shfl_xor(acc0[k], m, 64);
            acc1[k] += __shfl_xor(acc1[k], m, 64);
        }
    }
    if (pl == 0) {
        long base = (long)bid * 512;
#pragma unroll
        for (int k = 0; k < 16; ++k) {
            lamcp[base + k * 32 + 2 * vp]     = acc0[k];
            lamcp[base + k * 32 + 2 * vp + 1] = acc1[k];
        }
    }
    {
        int rr = tid >> 4, j = tid & 15;
        float s = 0.f;
        const float* er = es + rr * 512 + j * 32;
#pragma unroll 8
        for (int i = 0; i < 32; ++i) s += er[i];
#pragma unroll
        for (int m = 1; m < 16; m <<= 1) s += __shfl_xor(s, m, 64);
        if (j == 0) ws[O_ZP + (long)bid * 16 + rr] = s;
    }
}

// ---------------- finalize Z, fold BN into conv weights ----------------
__global__ __launch_bounds__(256) void kfin2(float* ws) {
    int tid = threadIdx.x;
    if (tid < 32) {
        int b = tid >> 4, kk = tid & 15;
        float s = 0.f;
        for (int c = 0; c < 216; ++c) s += ws[O_ZP + ((long)b * 216 + c) * 16 + kk];
        ws[O_RZI + tid] = 1.f / s;
    }
    for (int i = tid; i < 1728; i += 256) {
        int h = i / 432, r = i - h * 432, o = r >> 4, k = r & 15;
        ws[O_SW + i] = ws[O_SARR + h * 16 + k] * ws[O_WPT + o * 16 + k];
    }
    if (tid < 108) {
        int h = tid / 27, o = tid - h * 27;
        float s = 0.f;
        for (int k = 0; k < 16; ++k) s += ws[O_TARR + h * 16 + k] * ws[O_WPT + o * 16 + k];
        ws[O_CW + tid] = s;
    }
}

// ---------------- reduce lam_c partials + fold BN + 1/Z ----------------
__global__ __launch_bounds__(256) void klamcred(float* ws) {
    int out = blockIdx.x * 256 + threadIdx.x;
    if (out >= 1024) return;
    int b = out >> 9, idx = out & 511;
    int kk = idx >> 5, v = idx & 31;
    const float* lamcp = ws + O_LAMCP;
    float S = 0.f;
    for (int c = 0; c < 216; ++c) S += lamcp[((long)b * 216 + c) * 512 + idx];
    float sv = ws[O_SARR + 64 + v], tv = ws[O_TARR + 64 + v];
    ws[O_LAMC + out] = sv * S * ws[O_RZI + b * 16 + kk] + tv;
}

// ---------------- fold q-BN into lam_c ----------------
__global__ __launch_bounds__(256) void klamc3(float* ws) {
    int tid = threadIdx.x;
    for (int i = tid; i < 4096; i += 256) {
        int b = i >> 11, r = i & 2047;
        int h = r >> 9, k = (r >> 5) & 15, v = r & 31;
        ws[O_LAMC2 + i] = ws[O_SARR + h * 16 + k] * ws[O_LAMC + b * 512 + k * 32 + v];
    }
    {
        int i = tid;
        int b = i >> 7, h = (i >> 5) & 3, v = i & 31;
        float s = 0.f;
#pragma unroll
        for (int k = 0; k < 16; ++k) s += ws[O_TARR + h * 16 + k] * ws[O_LAMC + b * 512 + k * 32 + v];
        ws[O_BC + i] = s;
    }
}

// ---------------- final fused kernel ----------------
// tile (d,h,w) = (2,4,16) = 128 pos, 512 threads (8 waves), halo z = 0..431
__global__ __launch_bounds__(512, 4) void kfinal(const unsigned int* __restrict__ qu,
                                                 const unsigned int* __restrict__ vu,
                                                 const float* __restrict__ ws, float* __restrict__ y) {
    __shared__ unsigned int vbnu[432 * 16];      // [z][8 slots x 16B], swz sl^=((z^(z>>2))&3)
    __shared__ unsigned short qwh[27 * 128 * 4]; // [o][pos][h] bf16
    __shared__ unsigned int qsu[128 * 32];       // [pos][8 slots x 16B], swz sl^=(pos&7)
    const float* sarr  = ws + O_SARR;
    const float* tarr  = ws + O_TARR;
    const float* swp   = ws + O_SW;
    const float* cwp   = ws + O_CW;
    const float* lamc2 = ws + O_LAMC2;
    const float* bcp   = ws + O_BC;

    int bid0 = blockIdx.x;                    // XCD-aware bijective swizzle (grid 1728 = 8*216)
    int bid = (bid0 & 7) * 216 + (bid0 >> 3);
    int b = bid / 864, t = bid - b * 864;     // tiles: d 24 x h 12 x w 3
    int td = t / 36, r = t - td * 36;
    int th = r / 3, tw = r - th * 3;
    int d0 = td * 2, h0 = th * 4, w0 = tw * 16;
    int tid = threadIdx.x;

    // phase A: halo load of packed v -> BN -> bf16 pair, swizzled [z][v]
    for (int i = tid; i < 16 * 432; i += 512) {
        int vp = i / 432, z = i - vp * 432;
        int zd = z / 108, rr = z - zd * 108;
        int zh = rr / 18, zw = rr - zh * 18;
        int gd = d0 - 1 + zd, gh = h0 - 1 + zh, gw = w0 - 1 + zw;
        unsigned int out = 0u;
        if ((unsigned)gd < 48u && (unsigned)gh < 48u && (unsigned)gw < 48u) {
            unsigned int u = vu[((long)b * 16 + vp) * NPOS + gd * 2304 + gh * 48 + gw];
            float a = fmaf(bflo(u), sarr[64 + 2 * vp], tarr[64 + 2 * vp]);
            float c = fmaf(bfhi(u), sarr[65 + 2 * vp], tarr[65 + 2 * vp]);
            out = cvtpk(a, c);
        }
        int sl = (vp >> 2) ^ ((z ^ (z >> 2)) & 3);
        vbnu[z * 16 + sl * 4 + (vp & 3)] = out;
    }

    // phase B: qw + q stash
    int lane = tid & 63;
    int wv = __builtin_amdgcn_readfirstlane(tid >> 6);
    int hsel = wv & 3, psel = wv >> 2;
    int pos_l = psel * 64 + lane;
    int lh = lane >> 4, lw = lane & 15;
    int goff = (d0 + psel) * 2304 + (h0 + lh) * 48 + (w0 + lw);
    {
        unsigned int uq[8];
        float qk[16];
        const unsigned int* qb = qu + ((long)b * 32 + hsel * 8) * NPOS + goff;
#pragma unroll
        for (int m = 0; m < 8; ++m) {
            uq[m] = qb[(long)m * NPOS];
            qk[2 * m] = bflo(uq[m]);
            qk[2 * m + 1] = bfhi(uq[m]);
        }
#pragma unroll
        for (int o = 0; o < 27; ++o) {
            float a = cwp[hsel * 27 + o];
            const float* swrow = swp + (hsel * 27 + o) * 16;
#pragma unroll
            for (int k = 0; k < 16; ++k) a = fmaf(qk[k], swrow[k], a);
            qwh[(o * 128 + pos_l) * 4 + hsel] = (unsigned short)cvtpk(a, a);
        }
        uint4 w0v = make_uint4(uq[0], uq[1], uq[2], uq[3]);
        uint4 w1v = make_uint4(uq[4], uq[5], uq[6], uq[7]);
        *(uint4*)(qsu + pos_l * 32 + (((2 * hsel) ^ (pos_l & 7)) << 2)) = w0v;
        *(uint4*)(qsu + pos_l * 32 + (((2 * hsel + 1) ^ (pos_l & 7)) << 2)) = w1v;
    }
    __syncthreads();

    // phase C: (pos_l, v-group vg -> v0..v0+7), all 4 h
    int vg = wv & 3;
    int v0 = vg * 8;
    f32x2 acc2[4][4];
#pragma unroll
    for (int hh = 0; hh < 4; ++hh)
#pragma unroll
        for (int p = 0; p < 4; ++p) {
            acc2[hh][p][0] = bcp[(b * 4 + hh) * 32 + v0 + 2 * p];
            acc2[hh][p][1] = bcp[(b * 4 + hh) * 32 + v0 + 2 * p + 1];
        }

    // y_c: q (bf16 from LDS) x s_q-folded lam_c
#pragma unroll
    for (int s = 0; s < 8; ++s) {
        uint4 uq = *(const uint4*)(qsu + pos_l * 32 + ((s ^ (pos_l & 7)) << 2));
        int hh = s >> 1, k0 = (s & 1) * 8;
        float qa[8];
        qa[0] = bflo(uq.x); qa[1] = bfhi(uq.x);
        qa[2] = bflo(uq.y); qa[3] = bfhi(uq.y);
        qa[4] = bflo(uq.z); qa[5] = bfhi(uq.z);
        qa[6] = bflo(uq.w); qa[7] = bfhi(uq.w);
#pragma unroll
        for (int j = 0; j < 8; ++j) {
            const float* l2 = lamc2 + (((b * 4 + hh) * 16 + k0 + j) << 5) + v0;
#pragma unroll
            for (int p = 0; p < 4; ++p) {
                acc2[hh][p][0] = fmaf(qa[j], l2[2 * p], acc2[hh][p][0]);
                acc2[hh][p][1] = fmaf(qa[j], l2[2 * p + 1], acc2[hh][p][1]);
            }
        }
    }

    // y_p: 27-point stencil with packed-fp32 FMA
    int zb = psel * 108 + lh * 18 + lw;
#pragma unroll
    for (int od = 0; od < 3; ++od)
#pragma unroll
    for (int oh = 0; oh < 3; ++oh)
#pragma unroll
    for (int ow = 0; ow < 3; ++ow) {
        int o = od * 9 + oh * 3 + ow;
        int z = zb + od * 108 + oh * 18 + ow;
        int sl = vg ^ ((z ^ (z >> 2)) & 3);
        uint4 u = *(const uint4*)(vbnu + z * 16 + (sl << 2));
        uint2 uqw = *(const uint2*)(qwh + ((o * 128 + pos_l) << 2));
        f32x2 s0; s0[0] = bflo(u.x); s0[1] = bfhi(u.x);
        f32x2 s1; s1[0] = bflo(u.y); s1[1] = bfhi(u.y);
        f32x2 s2; s2[0] = bflo(u.z); s2[1] = bfhi(u.z);
        f32x2 s3; s3[0] = bflo(u.w); s3[1] = bfhi(u.w);
        float q0 = bflo(uqw.x), q1 = bfhi(uqw.x);
        float q2 = bflo(uqw.y), q3 = bfhi(uqw.y);
        f32x2 qd0; qd0[0] = q0; qd0[1] = q0;
        f32x2 qd1; qd1[0] = q1; qd1[1] = q1;
        f32x2 qd2; qd2[0] = q2; qd2[1] = q2;
        f32x2 qd3; qd3[0] = q3; qd3[1] = q3;
        pkfma(acc2[0][0], qd0, s0); pkfma(acc2[0][1], qd0, s1);
        pkfma(acc2[0][2], qd0, s2); pkfma(acc2[0][3], qd0, s3);
        pkfma(acc2[1][0], qd1, s0); pkfma(acc2[1][1], qd1, s1);
        pkfma(acc2[1][2], qd1, s2); pkfma(acc2[1][3], qd1, s3);
        pkfma(acc2[2][0], qd2, s0); pkfma(acc2[2][1], qd2, s1);
        pkfma(acc2[2][2], qd2, s2); pkfma(acc2[2][3], qd2, s3);
        pkfma(acc2[3][0], qd3, s0); pkfma(acc2[3][1], qd3, s1);
        pkfma(acc2[3][2], qd3, s2); pkfma(acc2[3][3], qd3, s3);
    }

    long pbase = (long)b * 128 * NPOS + goff;
#pragma unroll
    for (int hh = 0; hh < 4; ++hh)
#pragma unroll
        for (int p = 0; p < 4; ++p) {
            y[pbase + (long)(hh * 32 + v0 + 2 * p) * NPOS]     = acc2[hh][p][0];
            y[pbase + (long)(hh * 32 + v0 + 2 * p + 1) * NPOS] = acc2[hh][p][1];
        }
}

extern "C" void kernel_launch(void* const* d_in, const int* in_sizes, int n_in,
                              void* d_out, int out_size, void* d_ws, size_t ws_size,
                              hipStream_t stream) {
    const float* x    = (const float*)d_in[0];
    const float* Wq   = (const float*)d_in[1];
    const float* Wk   = (const float*)d_in[2];
    const float* Wv   = (const float*)d_in[3];
    const float* Wpos = (const float*)d_in[4];
    const float* gq   = (const float*)d_in[5];
    const float* bq   = (const float*)d_in[6];
    const float* gv   = (const float*)d_in[7];
    const float* bv   = (const float*)d_in[8];
    float* ws = (float*)d_ws;
    float* y  = (float*)d_out;
    unsigned int* qu = (unsigned int*)(ws + O_Q);
    float*        kr = ws + O_K;
    unsigned int* vu = (unsigned int*)(ws + O_V);
    // partial-sum scratch inside d_out (fully overwritten by kfinal afterwards)
    float* PS = y;                 // [3456][112]
    float* PQ = y + 387072;        // [3456][112]
    float* PM = y + 774144;        // [3456][16]

    ksetup  <<<30,   256, 0, stream>>>(Wq, Wk, Wv, Wpos, ws);
    kproj   <<<3456, 256, 0, stream>>>(x, ws, qu, kr, vu, PS, PQ, PM);
    kred    <<<128,  256, 0, stream>>>(PS, PQ, PM, gq, bq, gv, bv, ws);
    klamcp  <<<432,  256, 0, stream>>>(kr, vu, ws, ws + O_LAMCP);
    kfin2   <<<1,    256, 0, stream>>>(ws);
    klamcred<<<4,    256, 0, stream>>>(ws);
    klamc3  <<<1,    256, 0, stream>>>(ws);
    kfinal  <<<1728, 512, 0, stream>>>(qu, vu, ws, y);
}

// Round 12
// 221.691 us; speedup vs baseline: 2.3548x; 1.0819x over previous
//
#include <hip/hip_runtime.h>
#include <math.h>

#define NPOS 110592   // 48*48*48
#define EPS 1e-5f

using bf16x8 = __attribute__((ext_vector_type(8))) short;
using f32x4  = __attribute__((ext_vector_type(4))) float;
using f32x2  = __attribute__((ext_vector_type(2))) float;

// ws layout (float-slot offsets)
constexpr long O_WB    = 0;        // 112x128 bf16 = 7168 slots (W[oc][c])
constexpr long O_WPT   = 7168;     // 27*16 fp32 (wposT[o][k])
constexpr long O_SARR  = 7600;     // 96  (BN scale: 0..63 q, 64..95 v)
constexpr long O_TARR  = 7696;     // 96  (BN shift)
constexpr long O_RMAX  = 7792;     // 32  (softmax rowmax per (b,k))
constexpr long O_ZP    = 7824;     // 432*16 softmax denom partials
constexpr long O_RZI   = 14736;    // 32 (1/Z)
constexpr long O_SW    = 14768;    // 4*27*16 (s_q-folded conv weights)
constexpr long O_CW    = 16496;    // 108(+pad) (t_q-folded conv bias)
constexpr long O_LAMC  = 16608;    // 2*16*32
constexpr long O_LAMC2 = 17632;    // 2*4*16*32 (s_q-folded lam_c)
constexpr long O_BC    = 21728;    // 2*4*32 (t_q-folded lam_c bias)
constexpr long O_LAMCP = 21984;    // 2*216*512 lam_c partials
constexpr long O_Q     = 243168;   // u32[2][32][NPOS] bf16-pairs
constexpr long O_K     = 7321056;  // f32[2][16][NPOS]
constexpr long O_V     = 10860000; // u32[2][16][NPOS] bf16-pairs
// total ~57.6 MB

__device__ inline unsigned short f2bf(float f) {
    unsigned int u = __float_as_uint(f);
    u += 0x7FFFu + ((u >> 16) & 1u);   // RNE
    return (unsigned short)(u >> 16);
}
__device__ inline float bflo(unsigned int u) { return __uint_as_float(u << 16); }
__device__ inline float bfhi(unsigned int u) { return __uint_as_float(u & 0xFFFF0000u); }
__device__ inline unsigned int cvtpk(float a, float b) {
    unsigned int r;
    asm("v_cvt_pk_bf16_f32 %0, %1, %2" : "=v"(r) : "v"(a), "v"(b));
    return r;
}
__device__ inline void pkfma(f32x2& c, f32x2 a, f32x2 b) {
    asm("v_pk_fma_f32 %0, %1, %2, %0" : "+v"(c) : "v"(a), "v"(b));
}

// DPP row reductions (VALU pipe, no LDS): after the chain, lane 15 of each
// 16-lane row holds the row result. bound_ctrl=false -> invalid-source lanes
// keep their old value (results from those lanes are unused).
template<int CTRL>
__device__ inline float dpp_shr(float x) {
    int xi = __builtin_bit_cast(int, x);
    return __builtin_bit_cast(float, __builtin_amdgcn_update_dpp(xi, xi, CTRL, 0xf, 0xf, false));
}
__device__ inline float dpp_sum16(float x) {
    x += dpp_shr<0x111>(x);   // row_shr:1
    x += dpp_shr<0x112>(x);   // row_shr:2
    x += dpp_shr<0x114>(x);   // row_shr:4
    x += dpp_shr<0x118>(x);   // row_shr:8
    return x;                 // lane r==15 has the row sum
}
__device__ inline float dpp_max16(float x) {
    x = fmaxf(x, dpp_shr<0x111>(x));
    x = fmaxf(x, dpp_shr<0x112>(x));
    x = fmaxf(x, dpp_shr<0x114>(x));
    x = fmaxf(x, dpp_shr<0x118>(x));
    return x;                 // lane r==15 has the row max
}

// ---------------- setup: bf16 weights [oc][c] + wposT ----------------
__global__ __launch_bounds__(256) void ksetup(const float* Wq, const float* Wk, const float* Wv,
                                              const float* Wpos, float* ws) {
    int i = blockIdx.x * 256 + threadIdx.x;
    if (i < 7168) {
        int oc = i >> 6, cp = i & 63;
        int c = 2 * cp;
        float v0, v1;
        if (oc < 64)      { v0 = Wq[oc * 128 + c];        v1 = Wq[oc * 128 + c + 1]; }
        else if (oc < 80) { v0 = Wk[(oc - 64) * 128 + c]; v1 = Wk[(oc - 64) * 128 + c + 1]; }
        else              { v0 = Wv[(oc - 80) * 128 + c]; v1 = Wv[(oc - 80) * 128 + c + 1]; }
        ((unsigned int*)(ws + O_WB))[i] = (unsigned int)f2bf(v0) | ((unsigned int)f2bf(v1) << 16);
    } else if (i < 7600) {
        int j = i - 7168;
        int o = j >> 4, k = j & 15;
        ws[O_WPT + j] = Wpos[k * 27 + o];   // o = od*9+oh*3+ow
    }
}

// ---------------- projection via MFMA + fused stat partials (DPP reduce) ----------------
__global__ __launch_bounds__(256, 4) void kproj(const float* __restrict__ x, const float* __restrict__ ws,
                                                unsigned int* __restrict__ qu, float* __restrict__ kr,
                                                unsigned int* __restrict__ vu,
                                                float* __restrict__ PS, float* __restrict__ PQ,
                                                float* __restrict__ PM) {
    __shared__ unsigned int xsu[64 * 68];   // [pos][c] bf16
    __shared__ float pss[4 * 112], psq[4 * 112], pmx[4 * 16];
    const unsigned short* WBu = (const unsigned short*)(ws + O_WB);

    int blk0 = blockIdx.x;                // XCD-aware bijective swizzle (grid 3456 = 8*432)
    int blk = (blk0 & 7) * 432 + (blk0 >> 3);
    int b = blk / 1728, tile = blk - b * 1728;
    long base = (long)b * 128 * NPOS + (long)tile * 64;
    int tid = threadIdx.x;

    for (int i = tid; i < 64 * 64; i += 256) {
        int cp = i >> 6, p = i & 63;
        float v0 = x[base + (long)(2 * cp) * NPOS + p];
        float v1 = x[base + (long)(2 * cp + 1) * NPOS + p];
        xsu[p * 68 + cp] = cvtpk(v0, v1);
    }
    __syncthreads();

    int lane = tid & 63;
    int wv = __builtin_amdgcn_readfirstlane(tid >> 6);
    int r = lane & 15, g = lane >> 4;

    f32x4 acc[7];
#pragma unroll
    for (int t = 0; t < 7; ++t) acc[t] = (f32x4){0.f, 0.f, 0.f, 0.f};

    const unsigned short* xrow = (const unsigned short*)xsu + (wv * 16 + r) * 136;
#pragma unroll
    for (int ks = 0; ks < 4; ++ks) {
        bf16x8 bfrag = *(const bf16x8*)(const void*)(xrow + ks * 32 + g * 8);
#pragma unroll
        for (int t = 0; t < 7; ++t) {
            bf16x8 afrag = *(const bf16x8*)(const void*)(WBu + (t * 16 + r) * 128 + ks * 32 + g * 8);
            acc[t] = __builtin_amdgcn_mfma_f32_16x16x32_bf16(afrag, bfrag, acc[t], 0, 0, 0);
        }
    }

    long pos = (long)tile * 64 + wv * 16 + r;
    // q (t 0..3): bf16-pair u32
#pragma unroll
    for (int t = 0; t < 4; ++t)
#pragma unroll
        for (int jp = 0; jp < 2; ++jp)
            qu[((long)b * 32 + t * 8 + g * 2 + jp) * NPOS + pos] = cvtpk(acc[t][2 * jp], acc[t][2 * jp + 1]);
    // k (t=4): fp32
#pragma unroll
    for (int j = 0; j < 4; ++j)
        kr[((long)b * 16 + g * 4 + j) * NPOS + pos] = acc[4][j];
    // v (t 5..6): bf16-pair u32
#pragma unroll
    for (int t = 5; t < 7; ++t)
#pragma unroll
        for (int jp = 0; jp < 2; ++jp)
            vu[((long)b * 16 + (t - 5) * 8 + g * 2 + jp) * NPOS + pos] = cvtpk(acc[t][2 * jp], acc[t][2 * jp + 1]);

    // fused stat partials via DPP (VALU pipe); row result lands in lane r==15
#pragma unroll
    for (int t = 0; t < 7; ++t) {
#pragma unroll
        for (int j = 0; j < 4; ++j) {
            float v = acc[t][j];
            float s = dpp_sum16(v);
            float q = dpp_sum16(v * v);
            if (r == 15) {
                int oc = t * 16 + g * 4 + j;
                pss[wv * 112 + oc] = s;
                psq[wv * 112 + oc] = q;
            }
        }
    }
#pragma unroll
    for (int j = 0; j < 4; ++j) {
        float m = dpp_max16(acc[4][j]);
        if (r == 15) pmx[wv * 16 + g * 4 + j] = m;
    }
    __syncthreads();
    if (tid < 112) {
        float s = pss[tid] + pss[112 + tid] + pss[224 + tid] + pss[336 + tid];
        float q = psq[tid] + psq[112 + tid] + psq[224 + tid] + psq[336 + tid];
        PS[(long)blk * 112 + tid] = s;
        PQ[(long)blk * 112 + tid] = q;
    } else if (tid < 128) {
        int kk = tid - 112;
        PM[(long)blk * 16 + kk] = fmaxf(fmaxf(pmx[kk], pmx[16 + kk]),
                                        fmaxf(pmx[32 + kk], pmx[48 + kk]));
    }
}

// ---------------- reduce partials: BN scale/shift + k rowmax ----------------
__global__ __launch_bounds__(256) void kred(const float* __restrict__ PS, const float* __restrict__ PQ,
                                            const float* __restrict__ PM,
                                            const float* gq, const float* bq,
                                            const float* gv, const float* bv, float* ws) {
    __shared__ float rs[256], rq[256];
    int bid = blockIdx.x, tid = threadIdx.x;
    if (bid < 96) {
        int c = bid;
        int oc = c < 64 ? c : c + 16;
        float s = 0.f, q = 0.f;
        for (int i = tid; i < 3456; i += 256) {
            s += PS[(long)i * 112 + oc];
            q += PQ[(long)i * 112 + oc];
        }
        rs[tid] = s; rq[tid] = q;
        __syncthreads();
        for (int st = 128; st > 0; st >>= 1) {
            if (tid < st) { rs[tid] += rs[tid + st]; rq[tid] += rq[tid + st]; }
            __syncthreads();
        }
        if (tid == 0) {
            const float inv_n = 1.f / 221184.f;
            float mean = rs[0] * inv_n;
            float var = rq[0] * inv_n - mean * mean;
            float g = c < 64 ? gq[c] : gv[c - 64];
            float bb = c < 64 ? bq[c] : bv[c - 64];
            float sc = g * rsqrtf(var + EPS);
            ws[O_SARR + c] = sc;
            ws[O_TARR + c] = bb - mean * sc;
        }
    } else {
        int row = bid - 96;
        int b = row >> 4, kk = row & 15;
        float m = -1e30f;
        for (int i = tid; i < 1728; i += 256) m = fmaxf(m, PM[((long)b * 1728 + i) * 16 + kk]);
        rs[tid] = m;
        __syncthreads();
        for (int st = 128; st > 0; st >>= 1) {
            if (tid < st) rs[tid] = fmaxf(rs[tid], rs[tid + st]);
            __syncthreads();
        }
        if (tid == 0) ws[O_RMAX + row] = rs[0];
    }
}

// ---------------- lam_c partials + softmax Z partials ----------------
__global__ __launch_bounds__(256) void klamcp(const float* __restrict__ kr, const unsigned int* __restrict__ vu,
                                              float* __restrict__ ws, float* __restrict__ lamcp) {
    __shared__ float es[16 * 512];
    const float* rmax = ws + O_RMAX;
    int bid = blockIdx.x;                  // 0..431
    int b = bid / 216, chunk = bid - b * 216;
    long p0 = (long)chunk * 512;
    int tid = threadIdx.x;
    for (int i = tid; i < 16 * 512; i += 256) {
        int rr = i >> 9, p = i & 511;
        es[i] = expf(kr[((long)b * 16 + rr) * NPOS + p0 + p] - rmax[b * 16 + rr]);
    }
    __syncthreads();
    int vp = tid >> 4, pl = tid & 15;
    const unsigned int* vpp = vu + ((long)b * 16 + vp) * NPOS + p0;
    float acc0[16], acc1[16];
#pragma unroll
    for (int k = 0; k < 16; ++k) { acc0[k] = 0.f; acc1[k] = 0.f; }
    for (int j = 0; j < 32; ++j) {
        int p = pl + 16 * j;
        unsigned int u = vpp[p];
        float v0 = bflo(u), v1 = bfhi(u);
#pragma unroll
        for (int k = 0; k < 16; ++k) {
            float e = es[k * 512 + p];
            acc0[k] = fmaf(e, v0, acc0[k]);
            acc1[k] = fmaf(e, v1, acc1[k]);
        }
    }
#pragma unroll
    for (int m = 1; m < 16; m <<= 1) {
#pragma unroll
        for (int k = 0; k < 16; ++k) {
            acc0[k] += __shfl_xor(acc0[k], m, 64);
            acc1[k] += __shfl_xor(acc1[k], m, 64);
        }
    }
    if (pl == 0) {
        long base = (long)bid * 512;
#pragma unroll
        for (int k = 0; k < 16; ++k) {
            lamcp[base + k * 32 + 2 * vp]     = acc0[k];
            lamcp[base + k * 32 + 2 * vp + 1] = acc1[k];
        }
    }
    {
        int rr = tid >> 4, j = tid & 15;
        float s = 0.f;
        const float* er = es + rr * 512 + j * 32;
#pragma unroll 8
        for (int i = 0; i < 32; ++i) s += er[i];
#pragma unroll
        for (int m = 1; m < 16; m <<= 1) s += __shfl_xor(s, m, 64);
        if (j == 0) ws[O_ZP + (long)bid * 16 + rr] = s;
    }
}

// ---------------- finalize Z, fold BN into conv weights ----------------
__global__ __launch_bounds__(256) void kfin2(float* ws) {
    int tid = threadIdx.x;
    if (tid < 32) {
        int b = tid >> 4, kk = tid & 15;
        float s = 0.f;
        for (int c = 0; c < 216; ++c) s += ws[O_ZP + ((long)b * 216 + c) * 16 + kk];
        ws[O_RZI + tid] = 1.f / s;
    }
    for (int i = tid; i < 1728; i += 256) {
        int h = i / 432, r = i - h * 432, o = r >> 4, k = r & 15;
        ws[O_SW + i] = ws[O_SARR + h * 16 + k] * ws[O_WPT + o * 16 + k];
    }
    if (tid < 108) {
        int h = tid / 27, o = tid - h * 27;
        float s = 0.f;
        for (int k = 0; k < 16; ++k) s += ws[O_TARR + h * 16 + k] * ws[O_WPT + o * 16 + k];
        ws[O_CW + tid] = s;
    }
}

// ---------------- reduce lam_c partials + fold BN + 1/Z ----------------
__global__ __launch_bounds__(256) void klamcred(float* ws) {
    int out = blockIdx.x * 256 + threadIdx.x;
    if (out >= 1024) return;
    int b = out >> 9, idx = out & 511;
    int kk = idx >> 5, v = idx & 31;
    const float* lamcp = ws + O_LAMCP;
    float S = 0.f;
    for (int c = 0; c < 216; ++c) S += lamcp[((long)b * 216 + c) * 512 + idx];
    float sv = ws[O_SARR + 64 + v], tv = ws[O_TARR + 64 + v];
    ws[O_LAMC + out] = sv * S * ws[O_RZI + b * 16 + kk] + tv;
}

// ---------------- fold q-BN into lam_c ----------------
__global__ __launch_bounds__(256) void klamc3(float* ws) {
    int tid = threadIdx.x;
    for (int i = tid; i < 4096; i += 256) {
        int b = i >> 11, r = i & 2047;
        int h = r >> 9, k = (r >> 5) & 15, v = r & 31;
        ws[O_LAMC2 + i] = ws[O_SARR + h * 16 + k] * ws[O_LAMC + b * 512 + k * 32 + v];
    }
    {
        int i = tid;
        int b = i >> 7, h = (i >> 5) & 3, v = i & 31;
        float s = 0.f;
#pragma unroll
        for (int k = 0; k < 16; ++k) s += ws[O_TARR + h * 16 + k] * ws[O_LAMC + b * 512 + k * 32 + v];
        ws[O_BC + i] = s;
    }
}

// ---------------- final fused kernel ----------------
// tile (d,h,w) = (2,4,16) = 128 pos, 512 threads (8 waves), halo z = 0..431
__global__ __launch_bounds__(512, 4) void kfinal(const unsigned int* __restrict__ qu,
                                                 const unsigned int* __restrict__ vu,
                                                 const float* __restrict__ ws, float* __restrict__ y) {
    __shared__ unsigned int vbnu[432 * 16];      // [z][8 slots x 16B], swz sl^=((z^(z>>2))&3)
    __shared__ unsigned short qwh[27 * 128 * 4]; // [o][pos][h] bf16
    __shared__ unsigned int qsu[128 * 32];       // [pos][8 slots x 16B], swz sl^=(pos&7)
    const float* sarr  = ws + O_SARR;
    const float* tarr  = ws + O_TARR;
    const float* swp   = ws + O_SW;
    const float* cwp   = ws + O_CW;
    const float* lamc2 = ws + O_LAMC2;
    const float* bcp   = ws + O_BC;

    int bid0 = blockIdx.x;                    // XCD-aware bijective swizzle (grid 1728 = 8*216)
    int bid = (bid0 & 7) * 216 + (bid0 >> 3);
    int b = bid / 864, t = bid - b * 864;     // tiles: d 24 x h 12 x w 3
    int td = t / 36, r = t - td * 36;
    int th = r / 3, tw = r - th * 3;
    int d0 = td * 2, h0 = th * 4, w0 = tw * 16;
    int tid = threadIdx.x;

    // phase A: halo load of packed v -> BN -> bf16 pair, swizzled [z][v]
    for (int i = tid; i < 16 * 432; i += 512) {
        int vp = i / 432, z = i - vp * 432;
        int zd = z / 108, rr = z - zd * 108;
        int zh = rr / 18, zw = rr - zh * 18;
        int gd = d0 - 1 + zd, gh = h0 - 1 + zh, gw = w0 - 1 + zw;
        unsigned int out = 0u;
        if ((unsigned)gd < 48u && (unsigned)gh < 48u && (unsigned)gw < 48u) {
            unsigned int u = vu[((long)b * 16 + vp) * NPOS + gd * 2304 + gh * 48 + gw];
            float a = fmaf(bflo(u), sarr[64 + 2 * vp], tarr[64 + 2 * vp]);
            float c = fmaf(bfhi(u), sarr[65 + 2 * vp], tarr[65 + 2 * vp]);
            out = cvtpk(a, c);
        }
        int sl = (vp >> 2) ^ ((z ^ (z >> 2)) & 3);
        vbnu[z * 16 + sl * 4 + (vp & 3)] = out;
    }

    // phase B: qw + q stash
    int lane = tid & 63;
    int wv = __builtin_amdgcn_readfirstlane(tid >> 6);
    int hsel = wv & 3, psel = wv >> 2;
    int pos_l = psel * 64 + lane;
    int lh = lane >> 4, lw = lane & 15;
    int goff = (d0 + psel) * 2304 + (h0 + lh) * 48 + (w0 + lw);
    {
        unsigned int uq[8];
        float qk[16];
        const unsigned int* qb = qu + ((long)b * 32 + hsel * 8) * NPOS + goff;
#pragma unroll
        for (int m = 0; m < 8; ++m) {
            uq[m] = qb[(long)m * NPOS];
            qk[2 * m] = bflo(uq[m]);
            qk[2 * m + 1] = bfhi(uq[m]);
        }
#pragma unroll
        for (int o = 0; o < 27; ++o) {
            float a = cwp[hsel * 27 + o];
            const float* swrow = swp + (hsel * 27 + o) * 16;
#pragma unroll
            for (int k = 0; k < 16; ++k) a = fmaf(qk[k], swrow[k], a);
            qwh[(o * 128 + pos_l) * 4 + hsel] = (unsigned short)cvtpk(a, a);
        }
        uint4 w0v = make_uint4(uq[0], uq[1], uq[2], uq[3]);
        uint4 w1v = make_uint4(uq[4], uq[5], uq[6], uq[7]);
        *(uint4*)(qsu + pos_l * 32 + (((2 * hsel) ^ (pos_l & 7)) << 2)) = w0v;
        *(uint4*)(qsu + pos_l * 32 + (((2 * hsel + 1) ^ (pos_l & 7)) << 2)) = w1v;
    }
    __syncthreads();

    // phase C: (pos_l, v-group vg -> v0..v0+7), all 4 h
    int vg = wv & 3;
    int v0 = vg * 8;
    f32x2 acc2[4][4];
#pragma unroll
    for (int hh = 0; hh < 4; ++hh)
#pragma unroll
        for (int p = 0; p < 4; ++p) {
            acc2[hh][p][0] = bcp[(b * 4 + hh) * 32 + v0 + 2 * p];
            acc2[hh][p][1] = bcp[(b * 4 + hh) * 32 + v0 + 2 * p + 1];
        }

    // y_c: q (bf16 from LDS) x s_q-folded lam_c
#pragma unroll
    for (int s = 0; s < 8; ++s) {
        uint4 uq = *(const uint4*)(qsu + pos_l * 32 + ((s ^ (pos_l & 7)) << 2));
        int hh = s >> 1, k0 = (s & 1) * 8;
        float qa[8];
        qa[0] = bflo(uq.x); qa[1] = bfhi(uq.x);
        qa[2] = bflo(uq.y); qa[3] = bfhi(uq.y);
        qa[4] = bflo(uq.z); qa[5] = bfhi(uq.z);
        qa[6] = bflo(uq.w); qa[7] = bfhi(uq.w);
#pragma unroll
        for (int j = 0; j < 8; ++j) {
            const float* l2 = lamc2 + (((b * 4 + hh) * 16 + k0 + j) << 5) + v0;
#pragma unroll
            for (int p = 0; p < 4; ++p) {
                acc2[hh][p][0] = fmaf(qa[j], l2[2 * p], acc2[hh][p][0]);
                acc2[hh][p][1] = fmaf(qa[j], l2[2 * p + 1], acc2[hh][p][1]);
            }
        }
    }

    // y_p: 27-point stencil with packed-fp32 FMA
    int zb = psel * 108 + lh * 18 + lw;
#pragma unroll
    for (int od = 0; od < 3; ++od)
#pragma unroll
    for (int oh = 0; oh < 3; ++oh)
#pragma unroll
    for (int ow = 0; ow < 3; ++ow) {
        int o = od * 9 + oh * 3 + ow;
        int z = zb + od * 108 + oh * 18 + ow;
        int sl = vg ^ ((z ^ (z >> 2)) & 3);
        uint4 u = *(const uint4*)(vbnu + z * 16 + (sl << 2));
        uint2 uqw = *(const uint2*)(qwh + ((o * 128 + pos_l) << 2));
        f32x2 s0; s0[0] = bflo(u.x); s0[1] = bfhi(u.x);
        f32x2 s1; s1[0] = bflo(u.y); s1[1] = bfhi(u.y);
        f32x2 s2; s2[0] = bflo(u.z); s2[1] = bfhi(u.z);
        f32x2 s3; s3[0] = bflo(u.w); s3[1] = bfhi(u.w);
        float q0 = bflo(uqw.x), q1 = bfhi(uqw.x);
        float q2 = bflo(uqw.y), q3 = bfhi(uqw.y);
        f32x2 qd0; qd0[0] = q0; qd0[1] = q0;
        f32x2 qd1; qd1[0] = q1; qd1[1] = q1;
        f32x2 qd2; qd2[0] = q2; qd2[1] = q2;
        f32x2 qd3; qd3[0] = q3; qd3[1] = q3;
        pkfma(acc2[0][0], qd0, s0); pkfma(acc2[0][1], qd0, s1);
        pkfma(acc2[0][2], qd0, s2); pkfma(acc2[0][3], qd0, s3);
        pkfma(acc2[1][0], qd1, s0); pkfma(acc2[1][1], qd1, s1);
        pkfma(acc2[1][2], qd1, s2); pkfma(acc2[1][3], qd1, s3);
        pkfma(acc2[2][0], qd2, s0); pkfma(acc2[2][1], qd2, s1);
        pkfma(acc2[2][2], qd2, s2); pkfma(acc2[2][3], qd2, s3);
        pkfma(acc2[3][0], qd3, s0); pkfma(acc2[3][1], qd3, s1);
        pkfma(acc2[3][2], qd3, s2); pkfma(acc2[3][3], qd3, s3);
    }

    long pbase = (long)b * 128 * NPOS + goff;
#pragma unroll
    for (int hh = 0; hh < 4; ++hh)
#pragma unroll
        for (int p = 0; p < 4; ++p) {
            y[pbase + (long)(hh * 32 + v0 + 2 * p) * NPOS]     = acc2[hh][p][0];
            y[pbase + (long)(hh * 32 + v0 + 2 * p + 1) * NPOS] = acc2[hh][p][1];
        }
}

extern "C" void kernel_launch(void* const* d_in, const int* in_sizes, int n_in,
                              void* d_out, int out_size, void* d_ws, size_t ws_size,
                              hipStream_t stream) {
    const float* x    = (const float*)d_in[0];
    const float* Wq   = (const float*)d_in[1];
    const float* Wk   = (const float*)d_in[2];
    const float* Wv   = (const float*)d_in[3];
    const float* Wpos = (const float*)d_in[4];
    const float* gq   = (const float*)d_in[5];
    const float* bq   = (const float*)d_in[6];
    const float* gv   = (const float*)d_in[7];
    const float* bv   = (const float*)d_in[8];
    float* ws = (float*)d_ws;
    float* y  = (float*)d_out;
    unsigned int* qu = (unsigned int*)(ws + O_Q);
    float*        kr = ws + O_K;
    unsigned int* vu = (unsigned int*)(ws + O_V);
    // partial-sum scratch inside d_out (fully overwritten by kfinal afterwards)
    float* PS = y;                 // [3456][112]
    float* PQ = y + 387072;        // [3456][112]
    float* PM = y + 774144;        // [3456][16]

    ksetup  <<<30,   256, 0, stream>>>(Wq, Wk, Wv, Wpos, ws);
    kproj   <<<3456, 256, 0, stream>>>(x, ws, qu, kr, vu, PS, PQ, PM);
    kred    <<<128,  256, 0, stream>>>(PS, PQ, PM, gq, bq, gv, bv, ws);
    klamcp  <<<432,  256, 0, stream>>>(kr, vu, ws, ws + O_LAMCP);
    kfin2   <<<1,    256, 0, stream>>>(ws);
    klamcred<<<4,    256, 0, stream>>>(ws);
    klamc3  <<<1,    256, 0, stream>>>(ws);
    kfinal  <<<1728, 512, 0, stream>>>(qu, vu, ws, y);
}